// Round 11
// baseline (1460.753 us; speedup 1.0000x reference)
//
#include <hip/hip_runtime.h>

// Qwen3 forward: D=2048, N=16, K=8, H=128, F=6144, L=2, T=2048, V=32000
#define TT 2048
#define DD 2048
#define NHEAD 16
#define KHEAD 8
#define HDIM 128
#define FF 6144
#define LLAYERS 2
#define VV 32000

typedef __attribute__((ext_vector_type(8))) __bf16 bf16x8;
typedef __attribute__((ext_vector_type(4))) float f32x4;

__device__ __forceinline__ unsigned short f2bf(float x) {
  unsigned u = __float_as_uint(x);
  return (unsigned short)((u + 0x7FFFu + ((u >> 16) & 1u)) >> 16);
}

// f32 -> fp8 e4m3fn -> f32 round-trip (RNE), in-range weights only.
__device__ __forceinline__ float fp8_rt(float x) {
  float ax = fabsf(x);
  if (ax < 0.015625f) return rintf(x * 512.0f) * (1.0f / 512.0f);
  unsigned u = __float_as_uint(x);
  unsigned r = (u + 0x7FFFFu + ((u >> 20) & 1u)) & 0xFFF00000u;
  float y = __uint_as_float(r);
  if (fabsf(y) > 448.0f) y = copysignf(448.0f, x);
  return y;
}

__device__ __forceinline__ void gload16(const void* g, void* l) {
  __builtin_amdgcn_global_load_lds((__attribute__((address_space(1))) void*)g,
                                   (__attribute__((address_space(3))) void*)l,
                                   16, 0, 0);
}

// -------- embedding + RMSNorm(ln1, layer 0): ids -> h (f32) + xb (bf16) --------
__global__ void k_embed_rms(const int* __restrict__ ids, const float* __restrict__ embed,
                            const float* __restrict__ g, float* __restrict__ h,
                            unsigned short* __restrict__ out) {
  int t = blockIdx.x;
  const float4* src = (const float4*)(embed + (size_t)ids[t] * DD);
  float4 a = src[threadIdx.x], b = src[threadIdx.x + 256];
  float4* hrow = (float4*)(h + (size_t)t * DD);
  hrow[threadIdx.x] = a;
  hrow[threadIdx.x + 256] = b;
  float ss = a.x * a.x + a.y * a.y + a.z * a.z + a.w * a.w +
             b.x * b.x + b.y * b.y + b.z * b.z + b.w * b.w;
#pragma unroll
  for (int m = 32; m >= 1; m >>= 1) ss += __shfl_xor(ss, m);
  __shared__ float sred[4];
  int wid = threadIdx.x >> 6;
  if ((threadIdx.x & 63) == 0) sred[wid] = ss;
  __syncthreads();
  float tot = sred[0] + sred[1] + sred[2] + sred[3];
  float rn = 1.0f / sqrtf(tot * (1.0f / 2048.0f) + 1e-6f);
  const float4* gg = (const float4*)g;
  float4 g0 = gg[threadIdx.x], g1 = gg[threadIdx.x + 256];
  unsigned short* o0 = out + (size_t)t * DD + threadIdx.x * 4;
  unsigned short* o1 = o0 + 1024;
  *(ushort4*)o0 = make_ushort4(f2bf(a.x * rn * g0.x), f2bf(a.y * rn * g0.y),
                               f2bf(a.z * rn * g0.z), f2bf(a.w * rn * g0.w));
  *(ushort4*)o1 = make_ushort4(f2bf(b.x * rn * g1.x), f2bf(b.y * rn * g1.y),
                               f2bf(b.z * rn * g1.z), f2bf(b.w * rn * g1.w));
}

// ---------------- row RMSNorm (D=2048), f32 in -> bf16 out ----------------
__global__ void k_rmsnorm(const float* __restrict__ h, const float* __restrict__ g,
                          unsigned short* __restrict__ out) {
  int t = blockIdx.x;
  const float4* row = (const float4*)(h + (size_t)t * DD);
  float4 a = row[threadIdx.x], b = row[threadIdx.x + 256];
  float ss = a.x * a.x + a.y * a.y + a.z * a.z + a.w * a.w +
             b.x * b.x + b.y * b.y + b.z * b.z + b.w * b.w;
#pragma unroll
  for (int m = 32; m >= 1; m >>= 1) ss += __shfl_xor(ss, m);
  __shared__ float sred[4];
  int wid = threadIdx.x >> 6;
  if ((threadIdx.x & 63) == 0) sred[wid] = ss;
  __syncthreads();
  float tot = sred[0] + sred[1] + sred[2] + sred[3];
  float rn = 1.0f / sqrtf(tot * (1.0f / 2048.0f) + 1e-6f);
  const float4* gg = (const float4*)g;
  float4 g0 = gg[threadIdx.x], g1 = gg[threadIdx.x + 256];
  unsigned short* o0 = out + (size_t)t * DD + threadIdx.x * 4;
  unsigned short* o1 = o0 + 1024;
  *(ushort4*)o0 = make_ushort4(f2bf(a.x * rn * g0.x), f2bf(a.y * rn * g0.y),
                               f2bf(a.z * rn * g0.z), f2bf(a.w * rn * g0.w));
  *(ushort4*)o1 = make_ushort4(f2bf(b.x * rn * g1.x), f2bf(b.y * rn * g1.y),
                               f2bf(b.z * rn * g1.z), f2bf(b.w * rn * g1.w));
}

// -------- split-K reduce + residual + RMSNorm(next g): h += (sum p)*ds; xb = rms(h)*g --------
__global__ void k_sred_rms(const float* __restrict__ dp, const float* __restrict__ ds,
                           float* __restrict__ h, const float* __restrict__ g,
                           unsigned short* __restrict__ out) {
  int t = blockIdx.x;
  float4* hrow = (float4*)(h + (size_t)t * DD);
  float4 a = hrow[threadIdx.x], b = hrow[threadIdx.x + 256];
  float4 pa = {0.f, 0.f, 0.f, 0.f}, pb = {0.f, 0.f, 0.f, 0.f};
#pragma unroll
  for (int s = 0; s < 4; ++s) {
    const float4* pr = (const float4*)(dp + ((size_t)s * TT + t) * DD);
    float4 va = pr[threadIdx.x], vb = pr[threadIdx.x + 256];
    pa.x += va.x; pa.y += va.y; pa.z += va.z; pa.w += va.w;
    pb.x += vb.x; pb.y += vb.y; pb.z += vb.z; pb.w += vb.w;
  }
  const float4* dsc = (const float4*)ds;
  float4 s0 = dsc[threadIdx.x], s1 = dsc[threadIdx.x + 256];
  a.x += pa.x * s0.x; a.y += pa.y * s0.y; a.z += pa.z * s0.z; a.w += pa.w * s0.w;
  b.x += pb.x * s1.x; b.y += pb.y * s1.y; b.z += pb.z * s1.z; b.w += pb.w * s1.w;
  hrow[threadIdx.x] = a;
  hrow[threadIdx.x + 256] = b;
  float ss = a.x * a.x + a.y * a.y + a.z * a.z + a.w * a.w +
             b.x * b.x + b.y * b.y + b.z * b.z + b.w * b.w;
#pragma unroll
  for (int m = 32; m >= 1; m >>= 1) ss += __shfl_xor(ss, m);
  __shared__ float sred[4];
  int wid = threadIdx.x >> 6;
  if ((threadIdx.x & 63) == 0) sred[wid] = ss;
  __syncthreads();
  float tot = sred[0] + sred[1] + sred[2] + sred[3];
  float rn = 1.0f / sqrtf(tot * (1.0f / 2048.0f) + 1e-6f);
  const float4* gg = (const float4*)g;
  float4 g0 = gg[threadIdx.x], g1 = gg[threadIdx.x + 256];
  unsigned short* o0 = out + (size_t)t * DD + threadIdx.x * 4;
  unsigned short* o1 = o0 + 1024;
  *(ushort4*)o0 = make_ushort4(f2bf(a.x * rn * g0.x), f2bf(a.y * rn * g0.y),
                               f2bf(a.z * rn * g0.z), f2bf(a.w * rn * g0.w));
  *(ushort4*)o1 = make_ushort4(f2bf(b.x * rn * g1.x), f2bf(b.y * rn * g1.y),
                               f2bf(b.z * rn * g1.z), f2bf(b.w * rn * g1.w));
}

// -------- weight convert body: W[Kd=2048][Nd] f32 -> Wt[Nd][2048] bf16 --------
template <bool QUANT>
__device__ __forceinline__ void wconv_body(const float* W, unsigned short* Wt,
                                           int Kd, int Nd, int bx, int by) {
  __shared__ float tile[64][65];
  int k0 = by * 64, n0 = bx * 64;
  int t = threadIdx.x;  // 256
#pragma unroll
  for (int i = 0; i < 4; ++i) {
    int row = (t >> 4) + i * 16, c4 = (t & 15) * 4;
    float4 v = *(const float4*)&W[(size_t)(k0 + row) * Nd + n0 + c4];
    tile[row][c4] = v.x; tile[row][c4 + 1] = v.y;
    tile[row][c4 + 2] = v.z; tile[row][c4 + 3] = v.w;
  }
  __syncthreads();
#pragma unroll
  for (int i = 0; i < 2; ++i) {
    int n = (t >> 3) + i * 32, kc = (t & 7) * 8;
    unsigned short r[8];
#pragma unroll
    for (int j = 0; j < 8; ++j) {
      float x = tile[kc + j][n];
      if (QUANT) x = fp8_rt(x);
      r[j] = f2bf(x);
    }
    unsigned short* o = &Wt[(size_t)(n0 + n) * Kd + k0 + kc];
    *(ushort4*)o = make_ushort4(r[0], r[1], r[2], r[3]);
    *(ushort4*)(o + 4) = make_ushort4(r[4], r[5], r[6], r[7]);
  }
}

template <bool QUANT>
__global__ void k_wconv(const float* __restrict__ W, unsigned short* __restrict__ Wt,
                        int Kd, int Nd) {
  wconv_body<QUANT>(W, Wt, Kd, Nd, blockIdx.x, blockIdx.y);
}

// -------- merged q|k|v weight convert (1 launch, 2048 blocks) --------
__global__ void k_wconv_qkv(const float* __restrict__ qw, const float* __restrict__ kw,
                            const float* __restrict__ vw, unsigned short* __restrict__ Wt) {
  int b = blockIdx.x;
  if (b < 1024) {
    wconv_body<false>(qw, Wt, DD, 2048, b & 31, b >> 5);
  } else if (b < 1536) {
    int lb = b - 1024;
    wconv_body<false>(kw, Wt + (size_t)2048 * DD, DD, 1024, lb & 15, lb >> 4);
  } else {
    int lb = b - 1536;
    wconv_body<false>(vw, Wt + (size_t)3072 * DD, DD, 1024, lb & 15, lb >> 4);
  }
}

// -------- merged gate|up convert with 16-col interleave (1 launch, 6144 blocks) --------
__device__ __forceinline__ void wconv_glu_body(const float* W, unsigned short* Wt,
                                               int bx, int by, int off) {
  __shared__ float tile[64][65];
  int k0 = by * 64, n0 = bx * 64;
  int t = threadIdx.x;
#pragma unroll
  for (int i = 0; i < 4; ++i) {
    int row = (t >> 4) + i * 16, c4 = (t & 15) * 4;
    float4 v = *(const float4*)&W[(size_t)(k0 + row) * FF + n0 + c4];
    tile[row][c4] = v.x; tile[row][c4 + 1] = v.y;
    tile[row][c4 + 2] = v.z; tile[row][c4 + 3] = v.w;
  }
  __syncthreads();
#pragma unroll
  for (int i = 0; i < 2; ++i) {
    int n = (t >> 3) + i * 32, kc = (t & 7) * 8;
    unsigned short r[8];
#pragma unroll
    for (int j = 0; j < 8; ++j) r[j] = f2bf(fp8_rt(tile[kc + j][n]));
    int lj = n0 + n;
    int phys = ((lj >> 4) << 5) + (lj & 15) + off;
    unsigned short* o = &Wt[(size_t)phys * DD + k0 + kc];
    *(ushort4*)o = make_ushort4(r[0], r[1], r[2], r[3]);
    *(ushort4*)(o + 4) = make_ushort4(r[4], r[5], r[6], r[7]);
  }
}

__global__ void k_wconv_glu2(const float* __restrict__ gw, const float* __restrict__ uw,
                             unsigned short* __restrict__ Wt) {
  int b = blockIdx.x;
  if (b < 3072) wconv_glu_body(gw, Wt, b % 96, b / 96, 0);
  else { int lb = b - 3072; wconv_glu_body(uw, Wt, lb % 96, lb / 96, 16); }
}

// ---------------- 128x128 GEMM (m97 structure), kept for o-proj ----------------
template <int EPI>
__global__ __launch_bounds__(256, 2) void k_gemm(
    const unsigned short* __restrict__ A, const unsigned short* __restrict__ Bt,
    int M, int N, int K, float* __restrict__ Cf, const float* __restrict__ scaleN) {
  __shared__ unsigned short Al[128 * 64];
  __shared__ unsigned short Bl[128 * 64];
  const int tid = threadIdx.x;
  const int lane = tid & 63, wid = tid >> 6;
  const int wm = wid >> 1, wn = wid & 1;
  const int l16 = lane & 15, lg = lane >> 4;
  const size_t m0 = (size_t)blockIdx.x * 128, n0 = (size_t)blockIdx.y * 128;
  f32x4 acc[4][4] = {};
  for (int k0 = 0; k0 < K; k0 += 64) {
    __syncthreads();
#pragma unroll
    for (int it = 0; it < 4; ++it) {
      int chunk = it * 256 + tid;
      int row = chunk >> 3, c8 = chunk & 7;
      const unsigned short* ga = A + (m0 + row) * (size_t)K + k0 + c8 * 8;
      const unsigned short* gb = Bt + (n0 + row) * (size_t)K + k0 + c8 * 8;
      int base = (it * 256 + wid * 64) * 8;
      gload16((const void*)ga, (void*)&Al[base]);
      gload16((const void*)gb, (void*)&Bl[base]);
    }
    __syncthreads();
#pragma unroll
    for (int kk = 0; kk < 2; ++kk) {
      bf16x8 af[4], bfr[4];
      const int kb = kk * 32 + lg * 8;
#pragma unroll
      for (int i = 0; i < 4; ++i)
        af[i] = *(const bf16x8*)&Al[(wm * 64 + i * 16 + l16) * 64 + kb];
#pragma unroll
      for (int i = 0; i < 4; ++i)
        bfr[i] = *(const bf16x8*)&Bl[(wn * 64 + i * 16 + l16) * 64 + kb];
#pragma unroll
      for (int mi = 0; mi < 4; ++mi)
#pragma unroll
        for (int ni = 0; ni < 4; ++ni)
          acc[mi][ni] = __builtin_amdgcn_mfma_f32_16x16x32_bf16(af[mi], bfr[ni],
                                                                acc[mi][ni], 0, 0, 0);
    }
  }
#pragma unroll
  for (int mi = 0; mi < 4; ++mi)
#pragma unroll
    for (int r = 0; r < 4; ++r) {
      size_t row = m0 + wm * 64 + mi * 16 + 4 * lg + r;
#pragma unroll
      for (int ni = 0; ni < 4; ++ni) {
        size_t col = n0 + wn * 64 + ni * 16 + l16;
        float v = acc[mi][ni][r];
        size_t idx = row * (size_t)N + col;
        if constexpr (EPI == 0) Cf[idx] = v;
        else if constexpr (EPI == 1) Cf[idx] += v;
        else Cf[idx] += v * scaleN[col];
      }
    }
}

// ========== 256x256 GEMM, ONE barrier per 4-phase span (wave-skew enabled) ==========
// Span A consumes buf0(tile t) while staging ONLY buf1(t+1) {Aev,Aod,Bev,Bod};
// span B symmetric. No cross-wave hazards inside a span -> per-phase barriers
// removed; vmcnt(0)+s_barrier only at buffer switch. Per-phase instruction
// stream (Gray-code reads, lgkm fences, setprio, MFMA order) identical to R4.
template <int PT, bool SYNC, class STG>
__device__ __forceinline__ void gphase(const char* smem, int BUF, int aRd, int bRd,
                                       bf16x8 (&af)[4][2], bf16x8 (&bfr)[2][2][2],
                                       f32x4 (&acc)[8][4], STG&& stage) {
  constexpr int MH = (PT >= 2) ? 1 : 0;
  constexpr int NH = (PT == 1 || PT == 2) ? 1 : 0;
  if constexpr (PT == 0 || PT == 2) {
#pragma unroll
    for (int m = 0; m < 4; ++m) {
      int abase = BUF + aRd + MH * 8192 + m * 2048;
      af[m][0] = *(const bf16x8*)(smem + abase);
      af[m][1] = *(const bf16x8*)(smem + (abase ^ 64));
    }
  }
  if constexpr (PT <= 1) {
#pragma unroll
    for (int n = 0; n < 2; ++n) {
      int bbase = BUF + bRd + NH * 4096 + n * 2048;
      bfr[NH][n][0] = *(const bf16x8*)(smem + bbase);
      bfr[NH][n][1] = *(const bf16x8*)(smem + (bbase ^ 64));
    }
  }
  stage();
  if constexpr (PT != 3) {
    asm volatile("s_waitcnt lgkmcnt(0)" ::: "memory");
    __builtin_amdgcn_sched_barrier(0);
  }
  __builtin_amdgcn_s_setprio(1);
#pragma unroll
  for (int kk = 0; kk < 2; ++kk)
#pragma unroll
    for (int m = 0; m < 4; ++m)
#pragma unroll
      for (int n = 0; n < 2; ++n)
        acc[MH * 4 + m][NH * 2 + n] = __builtin_amdgcn_mfma_f32_16x16x32_bf16(
            af[m][kk], bfr[NH][n][kk], acc[MH * 4 + m][NH * 2 + n], 0, 0, 0);
  __builtin_amdgcn_s_setprio(0);
  __builtin_amdgcn_sched_barrier(0);
  if constexpr (SYNC) {
    asm volatile("s_waitcnt vmcnt(0)" ::: "memory");
    __builtin_amdgcn_sched_barrier(0);
    __builtin_amdgcn_s_barrier();
    __builtin_amdgcn_sched_barrier(0);
  }
}

// EPI: 0 = f32 store (to Cv + split*TT*N), 1 = bf16 store, 2 = swiglu-fused bf16
template <int EPI>
__global__ __launch_bounds__(512, 2) void k_gemm256(
    const unsigned short* __restrict__ A, const unsigned short* __restrict__ Bt,
    int N, int Kstride, int Kloop, int S, void* __restrict__ Cv,
    const float* __restrict__ gs, const float* __restrict__ us) {
  extern __shared__ __align__(16) char smem[];
  const int tid = threadIdx.x;
  const int lane = tid & 63, wid = tid >> 6;
  const int wm = wid >> 2, wn = wid & 3;
  const int l16 = lane & 15, lg = lane >> 4;
  const int l8 = lane >> 3, s8 = lane & 7;

  // XCD-aware bijective block swizzle (m204)
  const int nwg = gridDim.x;
  const int q = nwg >> 3, r = nwg & 7;
  const int xcd = blockIdx.x & 7, loc = blockIdx.x >> 3;
  const int wg = (xcd < r ? xcd * (q + 1) : r * (q + 1) + (xcd - r) * q) + loc;
  const int bm = wg & 7;
  const int t_ = wg >> 3;
  const int split = t_ % S, bn = t_ / S;
  const size_t m0 = (size_t)bm * 256, n0 = (size_t)bn * 256;
  const size_t kofs = (size_t)split * Kloop;

  const char* Ag = (const char*)(A + m0 * (size_t)Kstride + kofs);
  const char* Bg = (const char*)(Bt + n0 * (size_t)Kstride + kofs);
  const size_t sKA = (size_t)Kstride * 128;  // 64 rows * Kstride * 2B
  const size_t sKB = (size_t)Kstride * 64;   // 32 rows * Kstride * 2B
  const size_t aA = (size_t)(wid * 8 + l8) * Kstride * 2 + (size_t)((s8 ^ l8) << 4);
  const size_t aB = (size_t)((wid & 3) * 8 + l8) * Kstride * 2 + (size_t)((s8 ^ l8) << 4);

  auto stgA = [&](int BUF, int p, int kt) {
    gload16(Ag + aA + (size_t)p * sKA + (size_t)kt * 128,
            smem + BUF + p * 8192 + wid * 1024);
  };
  auto stgB = [&](int BUF, int qa, int qb, int kt) {
    int qq = (wid < 4) ? qa : qb;
    gload16(Bg + aB + (size_t)qq * sKB + (size_t)kt * 128,
            smem + BUF + 32768 + qq * 4096 + (wid & 3) * 1024);
  };
  auto stAev = [&](int BUF, int kt) { stgA(BUF, 0, kt); stgA(BUF, 2, kt); };
  auto stAod = [&](int BUF, int kt) { stgA(BUF, 1, kt); stgA(BUF, 3, kt); };
  auto stBev = [&](int BUF, int kt) { stgB(BUF, 0, 2, kt); stgB(BUF, 4, 6, kt); };
  auto stBod = [&](int BUF, int kt) { stgB(BUF, 1, 3, kt); stgB(BUF, 5, 7, kt); };

  const int colx = (lg << 4) ^ ((l16 & 7) << 4);
  const int aRd = (wm * 128 + l16) * 128 + colx;
  const int bRd = 32768 + (wn * 64 + l16) * 128 + colx;

  f32x4 acc[8][4] = {};
  bf16x8 af[4][2];
  bf16x8 bfr[2][2][2];

  // prologue: stage tile0 fully into buf0; drain; barrier.
  stAev(0, 0); stAod(0, 0); stBev(0, 0); stBod(0, 0);
  asm volatile("s_waitcnt vmcnt(0)" ::: "memory");
  __builtin_amdgcn_s_barrier();

  const int NIT = Kloop >> 7;  // pairs of K-tiles
#pragma unroll 1
  for (int i = 0; i < NIT; ++i) {
    const int t1 = 2 * i + 1, t2 = 2 * i + 2;
    const bool more = (i + 1 < NIT);
    // span A: consume buf0 (tile 2i), stage buf1 (t1)
    gphase<0, false>(smem, 0, aRd, bRd, af, bfr, acc, [&] { stAev(65536, t1); });
    gphase<1, false>(smem, 0, aRd, bRd, af, bfr, acc, [&] { stAod(65536, t1); });
    gphase<2, false>(smem, 0, aRd, bRd, af, bfr, acc, [&] { stBev(65536, t1); });
    gphase<3, true >(smem, 0, aRd, bRd, af, bfr, acc, [&] { stBod(65536, t1); });
    // span B: consume buf1 (t1), stage buf0 (t2)
    gphase<0, false>(smem, 65536, aRd, bRd, af, bfr, acc, [&] { if (more) stAev(0, t2); });
    gphase<1, false>(smem, 65536, aRd, bRd, af, bfr, acc, [&] { if (more) stAod(0, t2); });
    gphase<2, false>(smem, 65536, aRd, bRd, af, bfr, acc, [&] { if (more) stBev(0, t2); });
    gphase<3, true >(smem, 65536, aRd, bRd, af, bfr, acc, [&] { if (more) stBod(0, t2); });
  }

  if constexpr (EPI == 2) {
    // interleaved gate/up: chunk q0 = (n0+wn*64)>>5 and q0+1; logical col = q*16+l16
    const int q0 = (int)((n0 + (size_t)wn * 64) >> 5);
    const float gsc0 = gs[q0 * 16 + l16], usc0 = us[q0 * 16 + l16];
    const float gsc1 = gs[(q0 + 1) * 16 + l16], usc1 = us[(q0 + 1) * 16 + l16];
    unsigned short* F = (unsigned short*)Cv;
#pragma unroll
    for (int m = 0; m < 8; ++m)
#pragma unroll
      for (int rr = 0; rr < 4; ++rr) {
        size_t row = m0 + wm * 128 + m * 16 + lg * 4 + rr;
        float g0 = acc[m][0][rr] * gsc0, u0 = acc[m][1][rr] * usc0;
        float g1 = acc[m][2][rr] * gsc1, u1 = acc[m][3][rr] * usc1;
        F[row * FF + q0 * 16 + l16] = f2bf((g0 / (1.0f + __expf(-g0))) * u0);
        F[row * FF + (q0 + 1) * 16 + l16] = f2bf((g1 / (1.0f + __expf(-g1))) * u1);
      }
  } else {
    char* Cb = (char*)Cv + (EPI == 0 ? (size_t)split * TT * N * 4 : 0);
#pragma unroll
    for (int m = 0; m < 8; ++m)
#pragma unroll
      for (int rr = 0; rr < 4; ++rr) {
        size_t row = m0 + wm * 128 + m * 16 + lg * 4 + rr;
#pragma unroll
        for (int n = 0; n < 4; ++n) {
          size_t col = n0 + wn * 64 + n * 16 + l16;
          float v = acc[m][n][rr];
          size_t idx = row * (size_t)N + col;
          if constexpr (EPI == 0) ((float*)Cb)[idx] = v;
          else ((unsigned short*)Cb)[idx] = f2bf(v);
        }
      }
  }
}

// ====== merged q-post | k-post | V-transpose (1 launch, 14336 blocks) ======
__device__ __forceinline__ void qk_post_body(const float* p0, const float* p1,
                                             const float* nscale, const int* pos,
                                             unsigned short* out, int nheads,
                                             int coloff, float qscale, int bx) {
  int gw = bx * 4 + (threadIdx.x >> 6);
  int t = gw / nheads, n = gw % nheads;
  int lane = threadIdx.x & 63;
  size_t base = (size_t)t * 4096 + coloff + n * HDIM;
  float x1 = p0[base + lane] + p1[base + lane];
  float x2 = p0[base + lane + 64] + p1[base + lane + 64];
  float ss = x1 * x1 + x2 * x2;
#pragma unroll
  for (int m = 32; m >= 1; m >>= 1) ss += __shfl_xor(ss, m);
  float rn = qscale / sqrtf(ss * (1.0f / 128.0f) + 1e-6f);
  x1 *= rn * nscale[lane];
  x2 *= rn * nscale[lane + 64];
  float p = (float)pos[t];
  float inv = powf(1.0e6f, -(float)lane / 64.0f);
  float fr = p * inv;
  float c = cosf(fr), s = sinf(fr);
  unsigned short* o = out + ((size_t)n * TT + t) * HDIM;
  o[lane] = f2bf(x1 * c - x2 * s);
  o[lane + 64] = f2bf(x2 * c + x1 * s);
}

__global__ void k_qkv_post(const float* __restrict__ p0, const float* __restrict__ p1,
                           const float* __restrict__ qn, const float* __restrict__ kn,
                           const int* __restrict__ pos, unsigned short* __restrict__ qb,
                           unsigned short* __restrict__ kb, unsigned short* __restrict__ vT,
                           float qscale) {
  int b = blockIdx.x;
  if (b < 8192) {
    qk_post_body(p0, p1, qn, pos, qb, NHEAD, 0, qscale, b);
  } else if (b < 12288) {
    qk_post_body(p0, p1, kn, pos, kb, KHEAD, 2048, 1.0f, b - 8192);
  } else {
    // V transpose: [T][4096 (+3072)] f32 partials -> bf16 [8][128][T]
    int lb = b - 12288;
    __shared__ float tile[32][33];
    int t0 = (lb & 63) * 32, h0 = (lb >> 6) * 32;
    int tx = threadIdx.x & 31, ty = threadIdx.x >> 5;
#pragma unroll
    for (int i = 0; i < 32; i += 8) {
      size_t idx = (size_t)(t0 + ty + i) * 4096 + 3072 + h0 + tx;
      tile[ty + i][tx] = p0[idx] + p1[idx];
    }
    __syncthreads();
    int kvh = h0 >> 7;
    int hh = h0 & 127;
#pragma unroll
    for (int i = 0; i < 32; i += 8) {
      float x = tile[tx][ty + i];
      vT[(size_t)kvh * HDIM * TT + (size_t)(hh + ty + i) * TT + t0 + tx] = f2bf(x);
    }
  }
}

// ====== flash attention, LDS-staged KV, complementary-pair balanced ======
__global__ __launch_bounds__(256, 2) void k_attn(
    const unsigned short* __restrict__ Qb, const unsigned short* __restrict__ Kb,
    const unsigned short* __restrict__ Vt, unsigned short* __restrict__ Ob) {
  __shared__ __align__(16) char kv[2][32768];           // [buf][ K 16KB | V 16KB ]
  __shared__ __align__(16) char Pl[4][2048];            // per-wave P [16][64] bf16
  const int tid = threadIdx.x;
  const int w = tid >> 6, lane = tid & 63;
  const int l16 = lane & 15, lg = lane >> 4;
  const int head = blockIdx.y, kvh = head >> 1;
  const int j = blockIdx.x;                             // 0..15
  const int rbase[2] = {j * 64 + w * 16, (31 - j) * 64 + w * 16};

  bf16x8 qf[2][4];
#pragma unroll
  for (int qg = 0; qg < 2; ++qg) {
    const unsigned short* Qrow = Qb + ((size_t)head * TT + rbase[qg] + l16) * HDIM;
#pragma unroll
    for (int kc = 0; kc < 4; ++kc) qf[qg][kc] = *(const bf16x8*)&Qrow[kc * 32 + lg * 8];
  }

  const char* Kh = (const char*)(Kb + (size_t)kvh * TT * HDIM);
  const char* Vh = (const char*)(Vt + (size_t)kvh * HDIM * TT);

  auto stage = [&](int buf, int t) {
    const int kt0 = t * 64;
    char* bk = kv[buf];
    char* bv = kv[buf] + 16384;
#pragma unroll
    for (int it = 0; it < 4; ++it) {
      int rowK = it * 16 + w * 4 + (lane >> 4);
      gload16(Kh + (size_t)(kt0 + rowK) * 256 + (((lane & 15) ^ (rowK & 7)) << 4),
              bk + (it * 256 + w * 64) * 16);
      int rowV = it * 32 + w * 8 + (lane >> 3);
      gload16(Vh + (size_t)rowV * (TT * 2) + (size_t)kt0 * 2 +
                  (((lane & 7) ^ (rowV & 7)) << 4),
              bv + (it * 256 + w * 64) * 16);
    }
  };

  f32x4 o[2][8] = {};
  float m_[2][4], l_[2][4];
#pragma unroll
  for (int qg = 0; qg < 2; ++qg)
#pragma unroll
    for (int r = 0; r < 4; ++r) { m_[qg][r] = -1e30f; l_[qg][r] = 0.0f; }
  char* Pw = Pl[w];

  const int nt = 32 - j;
  stage(0, 0);
  asm volatile("s_waitcnt vmcnt(0)" ::: "memory");
  __syncthreads();

#pragma unroll 1
  for (int t = 0; t < nt; ++t) {
    const int buf = t & 1;
    const int kt0 = t * 64;
    if (t + 1 < nt) stage(buf ^ 1, t + 1);
    const char* bk = kv[buf];
    const char* bv = kv[buf] + 16384;

#pragma unroll
    for (int qg = 0; qg < 2; ++qg) {
      if (qg == 0 && t > j) continue;
      f32x4 sg[4];
#pragma unroll
      for (int cg = 0; cg < 4; ++cg) {
        sg[cg] = f32x4{0.f, 0.f, 0.f, 0.f};
#pragma unroll
        for (int kc = 0; kc < 4; ++kc) {
          int row = cg * 16 + l16;
          int slot = kc * 4 + lg;
          bf16x8 kf = *(const bf16x8*)(bk + row * 256 + ((slot ^ (row & 7)) << 4));
          sg[cg] = __builtin_amdgcn_mfma_f32_16x16x32_bf16(qf[qg][kc], kf, sg[cg], 0, 0, 0);
        }
      }
      f32x4 mx;
#pragma unroll
      for (int r = 0; r < 4; ++r) {
        int row = rbase[qg] + 4 * lg + r;
        float a = sg[0][r]; if (kt0 + l16 > row) a = -1e30f; sg[0][r] = a;
        float b = sg[1][r]; if (kt0 + 16 + l16 > row) b = -1e30f; sg[1][r] = b;
        float c = sg[2][r]; if (kt0 + 32 + l16 > row) c = -1e30f; sg[2][r] = c;
        float d = sg[3][r]; if (kt0 + 48 + l16 > row) d = -1e30f; sg[3][r] = d;
        mx[r] = fmaxf(fmaxf(a, b), fmaxf(c, d));
      }
#pragma unroll
      for (int msk = 8; msk >= 1; msk >>= 1)
#pragma unroll
        for (int r = 0; r < 4; ++r) mx[r] = fmaxf(mx[r], __shfl_xor(mx[r], msk));
      float alpha[4];
#pragma unroll
      for (int r = 0; r < 4; ++r) {
        float mn = fmaxf(m_[qg][r], mx[r]);
        alpha[r] = __expf(m_[qg][r] - mn);
        m_[qg][r] = mn;
      }
      f32x4 rs;
#pragma unroll
      for (int r = 0; r < 4; ++r) {
        float s0 = __expf(sg[0][r] - m_[qg][r]);
        float s1 = __expf(sg[1][r] - m_[qg][r]);
        float s2 = __expf(sg[2][r] - m_[qg][r]);
        float s3 = __expf(sg[3][r] - m_[qg][r]);
        sg[0][r] = s0; sg[1][r] = s1; sg[2][r] = s2; sg[3][r] = s3;
        rs[r] = (s0 + s1) + (s2 + s3);
      }
#pragma unroll
      for (int msk = 8; msk >= 1; msk >>= 1)
#pragma unroll
        for (int r = 0; r < 4; ++r) rs[r] += __shfl_xor(rs[r], msk);
#pragma unroll
      for (int r = 0; r < 4; ++r) l_[qg][r] = l_[qg][r] * alpha[r] + rs[r];
#pragma unroll
      for (int hi = 0; hi < 8; ++hi)
#pragma unroll
        for (int r = 0; r < 4; ++r) o[qg][hi][r] *= alpha[r];

#pragma unroll
      for (int cg = 0; cg < 4; ++cg)
#pragma unroll
        for (int r = 0; r < 4; ++r) {
          int prow = 4 * lg + r;
          int slot = cg * 2 + (l16 >> 3);
          *(unsigned short*)(Pw + prow * 128 + ((slot ^ (prow & 7)) << 4) +
                             (l16 & 7) * 2) = f2bf(sg[cg][r]);
        }
      bf16x8 pf[2];
#pragma unroll
      for (int half = 0; half < 2; ++half) {
        int slot = half * 4 + lg;
        pf[half] = *(const bf16x8*)(Pw + l16 * 128 + ((slot ^ (l16 & 7)) << 4));
      }
#pragma unroll
      for (int hi = 0; hi < 8; ++hi) {
        int row = hi * 16 + l16;
#pragma unroll
        for (int half = 0; half < 2; ++half) {
          int slot = half * 4 + lg;
          bf16x8 vf = *(const bf16x8*)(bv + row * 128 + ((slot ^ (row & 7)) << 4));
          o[qg][hi] = __builtin_amdgcn_mfma_f32_16x16x32_bf16(pf[half], vf, o[qg][hi], 0, 0, 0);
        }
      }
    }
    asm volatile("s_waitcnt vmcnt(0)" ::: "memory");
    __syncthreads();
  }

#pragma unroll
  for (int qg = 0; qg < 2; ++qg)
#pragma unroll
    for (int r = 0; r < 4; ++r) {
      float inv = 1.0f / l_[qg][r];
      size_t t = rbase[qg] + 4 * lg + r;
#pragma unroll
      for (int hi = 0; hi < 8; ++hi)
        Ob[t * DD + head * HDIM + hi * 16 + l16] = f2bf(o[qg][hi][r] * inv);
    }
}

extern "C" void kernel_launch(void* const* d_in, const int* in_sizes, int n_in,
                              void* d_out, int out_size, void* d_ws, size_t ws_size,
                              hipStream_t stream) {
  (void)in_sizes; (void)n_in; (void)out_size; (void)ws_size;
  const int* ids = (const int*)d_in[0];
  const int* pos = (const int*)d_in[1];
  const float* embed = (const float*)d_in[2];
  const float* ln1 = (const float*)d_in[3];
  const float* q_w = (const float*)d_in[4];
  const float* q_norm = (const float*)d_in[5];
  const float* k_w = (const float*)d_in[6];
  const float* k_norm = (const float*)d_in[7];
  const float* v_w = (const float*)d_in[8];
  const float* o_w = (const float*)d_in[9];
  const float* ln2 = (const float*)d_in[10];
  const float* gate_w = (const float*)d_in[11];
  const float* gate_s = (const float*)d_in[12];
  const float* up_w = (const float*)d_in[13];
  const float* up_s = (const float*)d_in[14];
  const float* down_w = (const float*)d_in[15];
  const float* down_s = (const float*)d_in[16];
  const float* fnorm = (const float*)d_in[17];
  const float* lm = (const float*)d_in[18];

  hipFuncSetAttribute((const void*)k_gemm256<0>,
                      hipFuncAttributeMaxDynamicSharedMemorySize, 131072);
  hipFuncSetAttribute((const void*)k_gemm256<1>,
                      hipFuncAttributeMaxDynamicSharedMemorySize, 131072);
  hipFuncSetAttribute((const void*)k_gemm256<2>,
                      hipFuncAttributeMaxDynamicSharedMemorySize, 131072);

  char* p = (char*)d_ws;
  auto alloc = [&](size_t n) { char* r = p; p += (n + 255) & ~(size_t)255; return r; };
  unsigned short* wbuf = (unsigned short*)alloc((size_t)VV * DD * 2);  // 131 MB
  float* h = (float*)alloc((size_t)TT * DD * 4);
  unsigned short* xb = (unsigned short*)alloc((size_t)TT * DD * 2);
  float* qkvf = (float*)alloc((size_t)2 * TT * 4096 * 4);              // 67 MB (2 partials)
  unsigned short* qb = (unsigned short*)alloc((size_t)NHEAD * TT * HDIM * 2);
  unsigned short* kb = (unsigned short*)alloc((size_t)KHEAD * TT * HDIM * 2);
  unsigned short* vT = (unsigned short*)alloc((size_t)KHEAD * HDIM * TT * 2);
  unsigned short* ob = (unsigned short*)alloc((size_t)TT * DD * 2);
  unsigned short* fuse = (unsigned short*)alloc((size_t)TT * FF * 2);
  // overlay inside wbuf (131.07 MB): dpart (down split-K f32 partials, 67.1 MB)
  // at +56MiB: down weight uses [0,25.2M) -> ok
  float* dpart = (float*)((char*)wbuf + ((size_t)56 << 20));
  float* qpart1 = qkvf + (size_t)TT * 4096;
  const float sm = 0.08838834764831845f;  // 1/sqrt(128)

  k_embed_rms<<<TT, 256, 0, stream>>>(ids, embed, ln1, h, xb);
  for (int l = 0; l < LLAYERS; ++l) {
    // --- attention block: fused QKV GEMM (N=4096) split-K x2 on gemm256 ---
    k_wconv_qkv<<<2048, 256, 0, stream>>>(
        q_w + (size_t)l * DD * 2048, k_w + (size_t)l * DD * 1024,
        v_w + (size_t)l * DD * 1024, wbuf);
    k_gemm256<0><<<8 * (4096 / 256) * 2, 512, 131072, stream>>>(
        xb, wbuf, 4096, DD, 1024, 2, qkvf, nullptr, nullptr);
    k_qkv_post<<<14336, 256, 0, stream>>>(
        qkvf, qpart1, q_norm + (size_t)l * HDIM, k_norm + (size_t)l * HDIM, pos,
        qb, kb, vT, sm);
    k_attn<<<dim3(16, NHEAD), 256, 0, stream>>>(qb, kb, vT, ob);
    k_wconv<false><<<dim3(DD / 64, 2048 / 64), 256, 0, stream>>>(
        o_w + (size_t)l * 2048 * DD, wbuf, 2048, DD);
    k_gemm<1><<<dim3(TT / 128, DD / 128), 256, 0, stream>>>(
        ob, wbuf, TT, DD, 2048, h, nullptr);
    // --- MLP block: interleaved gate|up GEMM with fused swiglu epilogue ---
    k_rmsnorm<<<TT, 256, 0, stream>>>(h, ln2 + (size_t)l * DD, xb);
    k_wconv_glu2<<<6144, 256, 0, stream>>>(
        gate_w + (size_t)l * DD * FF, up_w + (size_t)l * DD * FF, wbuf);
    k_gemm256<2><<<8 * (12288 / 256), 512, 131072, stream>>>(
        xb, wbuf, 12288, DD, DD, 1, fuse, gate_s + (size_t)l * FF,
        up_s + (size_t)l * FF);
    k_wconv<true><<<dim3(DD / 64, FF / 64), 256, 0, stream>>>(
        down_w + (size_t)l * FF * DD, wbuf, FF, DD);
    k_gemm256<0><<<8 * (DD / 256) * 4, 512, 131072, stream>>>(
        fuse, wbuf, DD, FF, 1536, 4, dpart, nullptr, nullptr);
    const float* gnext = (l + 1 < LLAYERS) ? (ln1 + (size_t)(l + 1) * DD) : fnorm;
    k_sred_rms<<<TT, 256, 0, stream>>>(dpart, down_s + (size_t)l * DD, h, gnext, xb);
  }
  // --- lm_head on the 8-phase kernel ---
  k_wconv<false><<<dim3(VV / 64, DD / 64), 256, 0, stream>>>(lm, wbuf, DD, VV);
  k_gemm256<0><<<8 * (VV / 256), 512, 131072, stream>>>(
      xb, wbuf, VV, DD, DD, 1, d_out, nullptr, nullptr);
}

// Round 12
// 1145.196 us; speedup vs baseline: 1.2755x; 1.2755x over previous
//
#include <hip/hip_runtime.h>

// Qwen3 forward: D=2048, N=16, K=8, H=128, F=6144, L=2, T=2048, V=32000
#define TT 2048
#define DD 2048
#define NHEAD 16
#define KHEAD 8
#define HDIM 128
#define FF 6144
#define LLAYERS 2
#define VV 32000

typedef __attribute__((ext_vector_type(8))) __bf16 bf16x8;
typedef __attribute__((ext_vector_type(4))) float f32x4;

__device__ __forceinline__ unsigned short f2bf(float x) {
  unsigned u = __float_as_uint(x);
  return (unsigned short)((u + 0x7FFFu + ((u >> 16) & 1u)) >> 16);
}

// f32 -> fp8 e4m3fn -> f32 round-trip (RNE), in-range weights only.
__device__ __forceinline__ float fp8_rt(float x) {
  float ax = fabsf(x);
  if (ax < 0.015625f) return rintf(x * 512.0f) * (1.0f / 512.0f);
  unsigned u = __float_as_uint(x);
  unsigned r = (u + 0x7FFFFu + ((u >> 20) & 1u)) & 0xFFF00000u;
  float y = __uint_as_float(r);
  if (fabsf(y) > 448.0f) y = copysignf(448.0f, x);
  return y;
}

__device__ __forceinline__ void gload16(const void* g, void* l) {
  __builtin_amdgcn_global_load_lds((__attribute__((address_space(1))) void*)g,
                                   (__attribute__((address_space(3))) void*)l,
                                   16, 0, 0);
}

// -------- embedding + RMSNorm(ln1, layer 0): ids -> h (f32) + xb (bf16) --------
__global__ void k_embed_rms(const int* __restrict__ ids, const float* __restrict__ embed,
                            const float* __restrict__ g, float* __restrict__ h,
                            unsigned short* __restrict__ out) {
  int t = blockIdx.x;
  const float4* src = (const float4*)(embed + (size_t)ids[t] * DD);
  float4 a = src[threadIdx.x], b = src[threadIdx.x + 256];
  float4* hrow = (float4*)(h + (size_t)t * DD);
  hrow[threadIdx.x] = a;
  hrow[threadIdx.x + 256] = b;
  float ss = a.x * a.x + a.y * a.y + a.z * a.z + a.w * a.w +
             b.x * b.x + b.y * b.y + b.z * b.z + b.w * b.w;
#pragma unroll
  for (int m = 32; m >= 1; m >>= 1) ss += __shfl_xor(ss, m);
  __shared__ float sred[4];
  int wid = threadIdx.x >> 6;
  if ((threadIdx.x & 63) == 0) sred[wid] = ss;
  __syncthreads();
  float tot = sred[0] + sred[1] + sred[2] + sred[3];
  float rn = 1.0f / sqrtf(tot * (1.0f / 2048.0f) + 1e-6f);
  const float4* gg = (const float4*)g;
  float4 g0 = gg[threadIdx.x], g1 = gg[threadIdx.x + 256];
  unsigned short* o0 = out + (size_t)t * DD + threadIdx.x * 4;
  unsigned short* o1 = o0 + 1024;
  *(ushort4*)o0 = make_ushort4(f2bf(a.x * rn * g0.x), f2bf(a.y * rn * g0.y),
                               f2bf(a.z * rn * g0.z), f2bf(a.w * rn * g0.w));
  *(ushort4*)o1 = make_ushort4(f2bf(b.x * rn * g1.x), f2bf(b.y * rn * g1.y),
                               f2bf(b.z * rn * g1.z), f2bf(b.w * rn * g1.w));
}

// ---------------- row RMSNorm (D=2048), f32 in -> bf16 out ----------------
__global__ void k_rmsnorm(const float* __restrict__ h, const float* __restrict__ g,
                          unsigned short* __restrict__ out) {
  int t = blockIdx.x;
  const float4* row = (const float4*)(h + (size_t)t * DD);
  float4 a = row[threadIdx.x], b = row[threadIdx.x + 256];
  float ss = a.x * a.x + a.y * a.y + a.z * a.z + a.w * a.w +
             b.x * b.x + b.y * b.y + b.z * b.z + b.w * b.w;
#pragma unroll
  for (int m = 32; m >= 1; m >>= 1) ss += __shfl_xor(ss, m);
  __shared__ float sred[4];
  int wid = threadIdx.x >> 6;
  if ((threadIdx.x & 63) == 0) sred[wid] = ss;
  __syncthreads();
  float tot = sred[0] + sred[1] + sred[2] + sred[3];
  float rn = 1.0f / sqrtf(tot * (1.0f / 2048.0f) + 1e-6f);
  const float4* gg = (const float4*)g;
  float4 g0 = gg[threadIdx.x], g1 = gg[threadIdx.x + 256];
  unsigned short* o0 = out + (size_t)t * DD + threadIdx.x * 4;
  unsigned short* o1 = o0 + 1024;
  *(ushort4*)o0 = make_ushort4(f2bf(a.x * rn * g0.x), f2bf(a.y * rn * g0.y),
                               f2bf(a.z * rn * g0.z), f2bf(a.w * rn * g0.w));
  *(ushort4*)o1 = make_ushort4(f2bf(b.x * rn * g1.x), f2bf(b.y * rn * g1.y),
                               f2bf(b.z * rn * g1.z), f2bf(b.w * rn * g1.w));
}

// -------- split-K(4) reduce [+opt col scale] + residual + RMSNorm(next g) --------
__global__ void k_sred_rms(const float* __restrict__ dp, const float* __restrict__ ds,
                           float* __restrict__ h, const float* __restrict__ g,
                           unsigned short* __restrict__ out) {
  int t = blockIdx.x;
  float4* hrow = (float4*)(h + (size_t)t * DD);
  float4 a = hrow[threadIdx.x], b = hrow[threadIdx.x + 256];
  float4 pa = {0.f, 0.f, 0.f, 0.f}, pb = {0.f, 0.f, 0.f, 0.f};
#pragma unroll
  for (int s = 0; s < 4; ++s) {
    const float4* pr = (const float4*)(dp + ((size_t)s * TT + t) * DD);
    float4 va = pr[threadIdx.x], vb = pr[threadIdx.x + 256];
    pa.x += va.x; pa.y += va.y; pa.z += va.z; pa.w += va.w;
    pb.x += vb.x; pb.y += vb.y; pb.z += vb.z; pb.w += vb.w;
  }
  if (ds) {
    const float4* dsc = (const float4*)ds;
    float4 s0 = dsc[threadIdx.x], s1 = dsc[threadIdx.x + 256];
    pa.x *= s0.x; pa.y *= s0.y; pa.z *= s0.z; pa.w *= s0.w;
    pb.x *= s1.x; pb.y *= s1.y; pb.z *= s1.z; pb.w *= s1.w;
  }
  a.x += pa.x; a.y += pa.y; a.z += pa.z; a.w += pa.w;
  b.x += pb.x; b.y += pb.y; b.z += pb.z; b.w += pb.w;
  hrow[threadIdx.x] = a;
  hrow[threadIdx.x + 256] = b;
  float ss = a.x * a.x + a.y * a.y + a.z * a.z + a.w * a.w +
             b.x * b.x + b.y * b.y + b.z * b.z + b.w * b.w;
#pragma unroll
  for (int m = 32; m >= 1; m >>= 1) ss += __shfl_xor(ss, m);
  __shared__ float sred[4];
  int wid = threadIdx.x >> 6;
  if ((threadIdx.x & 63) == 0) sred[wid] = ss;
  __syncthreads();
  float tot = sred[0] + sred[1] + sred[2] + sred[3];
  float rn = 1.0f / sqrtf(tot * (1.0f / 2048.0f) + 1e-6f);
  const float4* gg = (const float4*)g;
  float4 g0 = gg[threadIdx.x], g1 = gg[threadIdx.x + 256];
  unsigned short* o0 = out + (size_t)t * DD + threadIdx.x * 4;
  unsigned short* o1 = o0 + 1024;
  *(ushort4*)o0 = make_ushort4(f2bf(a.x * rn * g0.x), f2bf(a.y * rn * g0.y),
                               f2bf(a.z * rn * g0.z), f2bf(a.w * rn * g0.w));
  *(ushort4*)o1 = make_ushort4(f2bf(b.x * rn * g1.x), f2bf(b.y * rn * g1.y),
                               f2bf(b.z * rn * g1.z), f2bf(b.w * rn * g1.w));
}

// -------- weight convert body: W[Kd][Nd] f32 -> Wt[Nd][Kd] bf16 --------
template <bool QUANT>
__device__ __forceinline__ void wconv_body(const float* W, unsigned short* Wt,
                                           int Kd, int Nd, int bx, int by) {
  __shared__ float tile[64][65];
  int k0 = by * 64, n0 = bx * 64;
  int t = threadIdx.x;  // 256
#pragma unroll
  for (int i = 0; i < 4; ++i) {
    int row = (t >> 4) + i * 16, c4 = (t & 15) * 4;
    float4 v = *(const float4*)&W[(size_t)(k0 + row) * Nd + n0 + c4];
    tile[row][c4] = v.x; tile[row][c4 + 1] = v.y;
    tile[row][c4 + 2] = v.z; tile[row][c4 + 3] = v.w;
  }
  __syncthreads();
#pragma unroll
  for (int i = 0; i < 2; ++i) {
    int n = (t >> 3) + i * 32, kc = (t & 7) * 8;
    unsigned short r[8];
#pragma unroll
    for (int j = 0; j < 8; ++j) {
      float x = tile[kc + j][n];
      if (QUANT) x = fp8_rt(x);
      r[j] = f2bf(x);
    }
    unsigned short* o = &Wt[(size_t)(n0 + n) * Kd + k0 + kc];
    *(ushort4*)o = make_ushort4(r[0], r[1], r[2], r[3]);
    *(ushort4*)(o + 4) = make_ushort4(r[4], r[5], r[6], r[7]);
  }
}

template <bool QUANT>
__global__ void k_wconv(const float* __restrict__ W, unsigned short* __restrict__ Wt,
                        int Kd, int Nd) {
  wconv_body<QUANT>(W, Wt, Kd, Nd, blockIdx.x, blockIdx.y);
}

// -------- merged q|k|v weight convert (1 launch, 2048 blocks) --------
__global__ void k_wconv_qkv(const float* __restrict__ qw, const float* __restrict__ kw,
                            const float* __restrict__ vw, unsigned short* __restrict__ Wt) {
  int b = blockIdx.x;
  if (b < 1024) {
    wconv_body<false>(qw, Wt, DD, 2048, b & 31, b >> 5);
  } else if (b < 1536) {
    int lb = b - 1024;
    wconv_body<false>(kw, Wt + (size_t)2048 * DD, DD, 1024, lb & 15, lb >> 4);
  } else {
    int lb = b - 1536;
    wconv_body<false>(vw, Wt + (size_t)3072 * DD, DD, 1024, lb & 15, lb >> 4);
  }
}

// -------- merged gate|up convert with 16-col interleave (1 launch, 6144 blocks) --------
__device__ __forceinline__ void wconv_glu_body(const float* W, unsigned short* Wt,
                                               int bx, int by, int off) {
  __shared__ float tile[64][65];
  int k0 = by * 64, n0 = bx * 64;
  int t = threadIdx.x;
#pragma unroll
  for (int i = 0; i < 4; ++i) {
    int row = (t >> 4) + i * 16, c4 = (t & 15) * 4;
    float4 v = *(const float4*)&W[(size_t)(k0 + row) * FF + n0 + c4];
    tile[row][c4] = v.x; tile[row][c4 + 1] = v.y;
    tile[row][c4 + 2] = v.z; tile[row][c4 + 3] = v.w;
  }
  __syncthreads();
#pragma unroll
  for (int i = 0; i < 2; ++i) {
    int n = (t >> 3) + i * 32, kc = (t & 7) * 8;
    unsigned short r[8];
#pragma unroll
    for (int j = 0; j < 8; ++j) r[j] = f2bf(fp8_rt(tile[kc + j][n]));
    int lj = n0 + n;
    int phys = ((lj >> 4) << 5) + (lj & 15) + off;
    unsigned short* o = &Wt[(size_t)phys * DD + k0 + kc];
    *(ushort4*)o = make_ushort4(r[0], r[1], r[2], r[3]);
    *(ushort4*)(o + 4) = make_ushort4(r[4], r[5], r[6], r[7]);
  }
}

__global__ void k_wconv_glu2(const float* __restrict__ gw, const float* __restrict__ uw,
                             unsigned short* __restrict__ Wt) {
  int b = blockIdx.x;
  if (b < 3072) wconv_glu_body(gw, Wt, b % 96, b / 96, 0);
  else { int lb = b - 3072; wconv_glu_body(uw, Wt, lb % 96, lb / 96, 16); }
}

// ================= 256x256 8-phase GEMM, 1 barrier/phase, split-K =================
// (FROZEN verified R4/R10 structure: MfmaUtil ~47, 0 spills, 0 conflicts)
template <int PT, bool VM, class STG>
__device__ __forceinline__ void gphase(const char* smem, int BUF, int aRd, int bRd,
                                       bf16x8 (&af)[4][2], bf16x8 (&bfr)[2][2][2],
                                       f32x4 (&acc)[8][4], STG&& stage, bool vmzero) {
  constexpr int MH = (PT >= 2) ? 1 : 0;
  constexpr int NH = (PT == 1 || PT == 2) ? 1 : 0;
  if constexpr (PT == 0 || PT == 2) {
#pragma unroll
    for (int m = 0; m < 4; ++m) {
      int abase = BUF + aRd + MH * 8192 + m * 2048;
      af[m][0] = *(const bf16x8*)(smem + abase);
      af[m][1] = *(const bf16x8*)(smem + (abase ^ 64));
    }
  }
  if constexpr (PT <= 1) {
#pragma unroll
    for (int n = 0; n < 2; ++n) {
      int bbase = BUF + bRd + NH * 4096 + n * 2048;
      bfr[NH][n][0] = *(const bf16x8*)(smem + bbase);
      bfr[NH][n][1] = *(const bf16x8*)(smem + (bbase ^ 64));
    }
  }
  stage();
  if (VM) {
    if (vmzero) asm volatile("s_waitcnt vmcnt(0)" ::: "memory");
    else        asm volatile("s_waitcnt vmcnt(4)" ::: "memory");
  }
  __builtin_amdgcn_sched_barrier(0);
  __builtin_amdgcn_s_barrier();
  if constexpr (PT != 3) {
    asm volatile("s_waitcnt lgkmcnt(0)" ::: "memory");
    __builtin_amdgcn_sched_barrier(0);
  }
  __builtin_amdgcn_s_setprio(1);
#pragma unroll
  for (int kk = 0; kk < 2; ++kk)
#pragma unroll
    for (int m = 0; m < 4; ++m)
#pragma unroll
      for (int n = 0; n < 2; ++n)
        acc[MH * 4 + m][NH * 2 + n] = __builtin_amdgcn_mfma_f32_16x16x32_bf16(
            af[m][kk], bfr[NH][n][kk], acc[MH * 4 + m][NH * 2 + n], 0, 0, 0);
  __builtin_amdgcn_s_setprio(0);
  __builtin_amdgcn_sched_barrier(0);
}

// EPI: 0 = f32 store (to Cv + split*TT*N), 1 = bf16 store, 2 = swiglu-fused bf16
template <int EPI>
__global__ __launch_bounds__(512, 2) void k_gemm256(
    const unsigned short* __restrict__ A, const unsigned short* __restrict__ Bt,
    int N, int Kstride, int Kloop, int S, void* __restrict__ Cv,
    const float* __restrict__ gs, const float* __restrict__ us) {
  extern __shared__ __align__(16) char smem[];
  const int tid = threadIdx.x;
  const int lane = tid & 63, wid = tid >> 6;
  const int wm = wid >> 2, wn = wid & 3;
  const int l16 = lane & 15, lg = lane >> 4;
  const int l8 = lane >> 3, s8 = lane & 7;

  // XCD-aware bijective block swizzle (m204)
  const int nwg = gridDim.x;
  const int q = nwg >> 3, r = nwg & 7;
  const int xcd = blockIdx.x & 7, loc = blockIdx.x >> 3;
  const int wg = (xcd < r ? xcd * (q + 1) : r * (q + 1) + (xcd - r) * q) + loc;
  const int bm = wg & 7;
  const int t_ = wg >> 3;
  const int split = t_ % S, bn = t_ / S;
  const size_t m0 = (size_t)bm * 256, n0 = (size_t)bn * 256;
  const size_t kofs = (size_t)split * Kloop;

  const char* Ag = (const char*)(A + m0 * (size_t)Kstride + kofs);
  const char* Bg = (const char*)(Bt + n0 * (size_t)Kstride + kofs);
  const size_t sKA = (size_t)Kstride * 128;  // 64 rows * Kstride * 2B
  const size_t sKB = (size_t)Kstride * 64;   // 32 rows * Kstride * 2B
  const size_t aA = (size_t)(wid * 8 + l8) * Kstride * 2 + (size_t)((s8 ^ l8) << 4);
  const size_t aB = (size_t)((wid & 3) * 8 + l8) * Kstride * 2 + (size_t)((s8 ^ l8) << 4);

  auto stgA = [&](int BUF, int p, int kt) {
    gload16(Ag + aA + (size_t)p * sKA + (size_t)kt * 128,
            smem + BUF + p * 8192 + wid * 1024);
  };
  auto stgB = [&](int BUF, int qa, int qb, int kt) {
    int qq = (wid < 4) ? qa : qb;
    gload16(Bg + aB + (size_t)qq * sKB + (size_t)kt * 128,
            smem + BUF + 32768 + qq * 4096 + (wid & 3) * 1024);
  };
  auto stAev = [&](int BUF, int kt) { stgA(BUF, 0, kt); stgA(BUF, 2, kt); };
  auto stAod = [&](int BUF, int kt) { stgA(BUF, 1, kt); stgA(BUF, 3, kt); };
  auto stBev = [&](int BUF, int kt) { stgB(BUF, 0, 2, kt); stgB(BUF, 4, 6, kt); };
  auto stBod = [&](int BUF, int kt) { stgB(BUF, 1, 3, kt); stgB(BUF, 5, 7, kt); };

  const int colx = (lg << 4) ^ ((l16 & 7) << 4);
  const int aRd = (wm * 128 + l16) * 128 + colx;
  const int bRd = 32768 + (wn * 64 + l16) * 128 + colx;

  f32x4 acc[8][4] = {};
  bf16x8 af[4][2];
  bf16x8 bfr[2][2][2];

  // prologue: buf0 fully (t0), buf1 B-halves (t1); A(t1) staged at ph1/ph2.
  stAev(0, 0); stAod(0, 0); stBev(0, 0); stBod(0, 0);
  stBev(65536, 1); stBod(65536, 1);
  asm volatile("s_waitcnt vmcnt(4)" ::: "memory");
  __builtin_amdgcn_s_barrier();

  const int NIT = Kloop >> 7;  // pairs of K-tiles
#pragma unroll 1
  for (int i = 0; i < NIT; ++i) {
    const int t1 = 2 * i + 1, t2 = 2 * i + 2, t3 = 2 * i + 3;
    const bool more = (i + 1 < NIT);
    gphase<0, false>(smem, 0, aRd, bRd, af, bfr, acc, [&] { stAev(65536, t1); }, false);
    gphase<1, false>(smem, 0, aRd, bRd, af, bfr, acc, [&] { stAod(65536, t1); }, false);
    gphase<2, false>(smem, 0, aRd, bRd, af, bfr, acc, [&] { if (more) stBev(0, t2); }, false);
    gphase<3, true >(smem, 0, aRd, bRd, af, bfr, acc, [&] { if (more) stBod(0, t2); }, !more);
    gphase<0, false>(smem, 65536, aRd, bRd, af, bfr, acc, [&] { if (more) stAev(0, t2); }, false);
    gphase<1, false>(smem, 65536, aRd, bRd, af, bfr, acc, [&] { if (more) stAod(0, t2); }, false);
    gphase<2, false>(smem, 65536, aRd, bRd, af, bfr, acc, [&] { if (more) stBev(65536, t3); }, false);
    gphase<3, true >(smem, 65536, aRd, bRd, af, bfr, acc, [&] { if (more) stBod(65536, t3); }, false);
  }

  if constexpr (EPI == 2) {
    const int q0 = (int)((n0 + (size_t)wn * 64) >> 5);
    const float gsc0 = gs[q0 * 16 + l16], usc0 = us[q0 * 16 + l16];
    const float gsc1 = gs[(q0 + 1) * 16 + l16], usc1 = us[(q0 + 1) * 16 + l16];
    unsigned short* F = (unsigned short*)Cv;
#pragma unroll
    for (int m = 0; m < 8; ++m)
#pragma unroll
      for (int rr = 0; rr < 4; ++rr) {
        size_t row = m0 + wm * 128 + m * 16 + lg * 4 + rr;
        float g0 = acc[m][0][rr] * gsc0, u0 = acc[m][1][rr] * usc0;
        float g1 = acc[m][2][rr] * gsc1, u1 = acc[m][3][rr] * usc1;
        F[row * FF + q0 * 16 + l16] = f2bf((g0 / (1.0f + __expf(-g0))) * u0);
        F[row * FF + (q0 + 1) * 16 + l16] = f2bf((g1 / (1.0f + __expf(-g1))) * u1);
      }
  } else {
    char* Cb = (char*)Cv + (EPI == 0 ? (size_t)split * TT * N * 4 : 0);
#pragma unroll
    for (int m = 0; m < 8; ++m)
#pragma unroll
      for (int rr = 0; rr < 4; ++rr) {
        size_t row = m0 + wm * 128 + m * 16 + lg * 4 + rr;
#pragma unroll
        for (int n = 0; n < 4; ++n) {
          size_t col = n0 + wn * 64 + n * 16 + l16;
          float v = acc[m][n][rr];
          size_t idx = row * (size_t)N + col;
          if constexpr (EPI == 0) ((float*)Cb)[idx] = v;
          else ((unsigned short*)Cb)[idx] = f2bf(v);
        }
      }
  }
}

// ====== merged q-post | k-post | V-transpose (1 launch, 14336 blocks) ======
__device__ __forceinline__ void qk_post_body(const float* p0, const float* p1,
                                             const float* nscale, const int* pos,
                                             unsigned short* out, int nheads,
                                             int coloff, float qscale, int bx) {
  int gw = bx * 4 + (threadIdx.x >> 6);
  int t = gw / nheads, n = gw % nheads;
  int lane = threadIdx.x & 63;
  size_t base = (size_t)t * 4096 + coloff + n * HDIM;
  float x1 = p0[base + lane] + p1[base + lane];
  float x2 = p0[base + lane + 64] + p1[base + lane + 64];
  float ss = x1 * x1 + x2 * x2;
#pragma unroll
  for (int m = 32; m >= 1; m >>= 1) ss += __shfl_xor(ss, m);
  float rn = qscale / sqrtf(ss * (1.0f / 128.0f) + 1e-6f);
  x1 *= rn * nscale[lane];
  x2 *= rn * nscale[lane + 64];
  float p = (float)pos[t];
  float inv = powf(1.0e6f, -(float)lane / 64.0f);
  float fr = p * inv;
  float c = cosf(fr), s = sinf(fr);
  unsigned short* o = out + ((size_t)n * TT + t) * HDIM;
  o[lane] = f2bf(x1 * c - x2 * s);
  o[lane + 64] = f2bf(x2 * c + x1 * s);
}

__global__ void k_qkv_post(const float* __restrict__ p0, const float* __restrict__ p1,
                           const float* __restrict__ qn, const float* __restrict__ kn,
                           const int* __restrict__ pos, unsigned short* __restrict__ qb,
                           unsigned short* __restrict__ kb, unsigned short* __restrict__ vT,
                           float qscale) {
  int b = blockIdx.x;
  if (b < 8192) {
    qk_post_body(p0, p1, qn, pos, qb, NHEAD, 0, qscale, b);
  } else if (b < 12288) {
    qk_post_body(p0, p1, kn, pos, kb, KHEAD, 2048, 1.0f, b - 8192);
  } else {
    int lb = b - 12288;
    __shared__ float tile[32][33];
    int t0 = (lb & 63) * 32, h0 = (lb >> 6) * 32;
    int tx = threadIdx.x & 31, ty = threadIdx.x >> 5;
#pragma unroll
    for (int i = 0; i < 32; i += 8) {
      size_t idx = (size_t)(t0 + ty + i) * 4096 + 3072 + h0 + tx;
      tile[ty + i][tx] = p0[idx] + p1[idx];
    }
    __syncthreads();
    int kvh = h0 >> 7;
    int hh = h0 & 127;
#pragma unroll
    for (int i = 0; i < 32; i += 8) {
      float x = tile[tx][ty + i];
      vT[(size_t)kvh * HDIM * TT + (size_t)(hh + ty + i) * TT + t0 + tx] = f2bf(x);
    }
  }
}

// ====== flash attention, LDS-staged KV, complementary-pair balanced ======
__global__ __launch_bounds__(256, 2) void k_attn(
    const unsigned short* __restrict__ Qb, const unsigned short* __restrict__ Kb,
    const unsigned short* __restrict__ Vt, unsigned short* __restrict__ Ob) {
  __shared__ __align__(16) char kv[2][32768];           // [buf][ K 16KB | V 16KB ]
  __shared__ __align__(16) char Pl[4][2048];            // per-wave P [16][64] bf16
  const int tid = threadIdx.x;
  const int w = tid >> 6, lane = tid & 63;
  const int l16 = lane & 15, lg = lane >> 4;
  const int head = blockIdx.y, kvh = head >> 1;
  const int j = blockIdx.x;                             // 0..15
  const int rbase[2] = {j * 64 + w * 16, (31 - j) * 64 + w * 16};

  bf16x8 qf[2][4];
#pragma unroll
  for (int qg = 0; qg < 2; ++qg) {
    const unsigned short* Qrow = Qb + ((size_t)head * TT + rbase[qg] + l16) * HDIM;
#pragma unroll
    for (int kc = 0; kc < 4; ++kc) qf[qg][kc] = *(const bf16x8*)&Qrow[kc * 32 + lg * 8];
  }

  const char* Kh = (const char*)(Kb + (size_t)kvh * TT * HDIM);
  const char* Vh = (const char*)(Vt + (size_t)kvh * HDIM * TT);

  auto stage = [&](int buf, int t) {
    const int kt0 = t * 64;
    char* bk = kv[buf];
    char* bv = kv[buf] + 16384;
#pragma unroll
    for (int it = 0; it < 4; ++it) {
      int rowK = it * 16 + w * 4 + (lane >> 4);
      gload16(Kh + (size_t)(kt0 + rowK) * 256 + (((lane & 15) ^ (rowK & 7)) << 4),
              bk + (it * 256 + w * 64) * 16);
      int rowV = it * 32 + w * 8 + (lane >> 3);
      gload16(Vh + (size_t)rowV * (TT * 2) + (size_t)kt0 * 2 +
                  (((lane & 7) ^ (rowV & 7)) << 4),
              bv + (it * 256 + w * 64) * 16);
    }
  };

  f32x4 o[2][8] = {};
  float m_[2][4], l_[2][4];
#pragma unroll
  for (int qg = 0; qg < 2; ++qg)
#pragma unroll
    for (int r = 0; r < 4; ++r) { m_[qg][r] = -1e30f; l_[qg][r] = 0.0f; }
  char* Pw = Pl[w];

  const int nt = 32 - j;
  stage(0, 0);
  asm volatile("s_waitcnt vmcnt(0)" ::: "memory");
  __syncthreads();

#pragma unroll 1
  for (int t = 0; t < nt; ++t) {
    const int buf = t & 1;
    const int kt0 = t * 64;
    if (t + 1 < nt) stage(buf ^ 1, t + 1);
    const char* bk = kv[buf];
    const char* bv = kv[buf] + 16384;

#pragma unroll
    for (int qg = 0; qg < 2; ++qg) {
      if (qg == 0 && t > j) continue;
      f32x4 sg[4];
#pragma unroll
      for (int cg = 0; cg < 4; ++cg) {
        sg[cg] = f32x4{0.f, 0.f, 0.f, 0.f};
#pragma unroll
        for (int kc = 0; kc < 4; ++kc) {
          int row = cg * 16 + l16;
          int slot = kc * 4 + lg;
          bf16x8 kf = *(const bf16x8*)(bk + row * 256 + ((slot ^ (row & 7)) << 4));
          sg[cg] = __builtin_amdgcn_mfma_f32_16x16x32_bf16(qf[qg][kc], kf, sg[cg], 0, 0, 0);
        }
      }
      f32x4 mx;
#pragma unroll
      for (int r = 0; r < 4; ++r) {
        int row = rbase[qg] + 4 * lg + r;
        float a = sg[0][r]; if (kt0 + l16 > row) a = -1e30f; sg[0][r] = a;
        float b = sg[1][r]; if (kt0 + 16 + l16 > row) b = -1e30f; sg[1][r] = b;
        float c = sg[2][r]; if (kt0 + 32 + l16 > row) c = -1e30f; sg[2][r] = c;
        float d = sg[3][r]; if (kt0 + 48 + l16 > row) d = -1e30f; sg[3][r] = d;
        mx[r] = fmaxf(fmaxf(a, b), fmaxf(c, d));
      }
#pragma unroll
      for (int msk = 8; msk >= 1; msk >>= 1)
#pragma unroll
        for (int r = 0; r < 4; ++r) mx[r] = fmaxf(mx[r], __shfl_xor(mx[r], msk));
      float alpha[4];
#pragma unroll
      for (int r = 0; r < 4; ++r) {
        float mn = fmaxf(m_[qg][r], mx[r]);
        alpha[r] = __expf(m_[qg][r] - mn);
        m_[qg][r] = mn;
      }
      f32x4 rs;
#pragma unroll
      for (int r = 0; r < 4; ++r) {
        float s0 = __expf(sg[0][r] - m_[qg][r]);
        float s1 = __expf(sg[1][r] - m_[qg][r]);
        float s2 = __expf(sg[2][r] - m_[qg][r]);
        float s3 = __expf(sg[3][r] - m_[qg][r]);
        sg[0][r] = s0; sg[1][r] = s1; sg[2][r] = s2; sg[3][r] = s3;
        rs[r] = (s0 + s1) + (s2 + s3);
      }
#pragma unroll
      for (int msk = 8; msk >= 1; msk >>= 1)
#pragma unroll
        for (int r = 0; r < 4; ++r) rs[r] += __shfl_xor(rs[r], msk);
#pragma unroll
      for (int r = 0; r < 4; ++r) l_[qg][r] = l_[qg][r] * alpha[r] + rs[r];
#pragma unroll
      for (int hi = 0; hi < 8; ++hi)
#pragma unroll
        for (int r = 0; r < 4; ++r) o[qg][hi][r] *= alpha[r];

#pragma unroll
      for (int cg = 0; cg < 4; ++cg)
#pragma unroll
        for (int r = 0; r < 4; ++r) {
          int prow = 4 * lg + r;
          int slot = cg * 2 + (l16 >> 3);
          *(unsigned short*)(Pw + prow * 128 + ((slot ^ (prow & 7)) << 4) +
                             (l16 & 7) * 2) = f2bf(sg[cg][r]);
        }
      bf16x8 pf[2];
#pragma unroll
      for (int half = 0; half < 2; ++half) {
        int slot = half * 4 + lg;
        pf[half] = *(const bf16x8*)(Pw + l16 * 128 + ((slot ^ (l16 & 7)) << 4));
      }
#pragma unroll
      for (int hi = 0; hi < 8; ++hi) {
        int row = hi * 16 + l16;
#pragma unroll
        for (int half = 0; half < 2; ++half) {
          int slot = half * 4 + lg;
          bf16x8 vf = *(const bf16x8*)(bv + row * 128 + ((slot ^ (row & 7)) << 4));
          o[qg][hi] = __builtin_amdgcn_mfma_f32_16x16x32_bf16(pf[half], vf, o[qg][hi], 0, 0, 0);
        }
      }
    }
    asm volatile("s_waitcnt vmcnt(0)" ::: "memory");
    __syncthreads();
  }

#pragma unroll
  for (int qg = 0; qg < 2; ++qg)
#pragma unroll
    for (int r = 0; r < 4; ++r) {
      float inv = 1.0f / l_[qg][r];
      size_t t = rbase[qg] + 4 * lg + r;
#pragma unroll
      for (int hi = 0; hi < 8; ++hi)
        Ob[t * DD + head * HDIM + hi * 16 + l16] = f2bf(o[qg][hi][r] * inv);
    }
}

extern "C" void kernel_launch(void* const* d_in, const int* in_sizes, int n_in,
                              void* d_out, int out_size, void* d_ws, size_t ws_size,
                              hipStream_t stream) {
  (void)in_sizes; (void)n_in; (void)out_size; (void)ws_size;
  const int* ids = (const int*)d_in[0];
  const int* pos = (const int*)d_in[1];
  const float* embed = (const float*)d_in[2];
  const float* ln1 = (const float*)d_in[3];
  const float* q_w = (const float*)d_in[4];
  const float* q_norm = (const float*)d_in[5];
  const float* k_w = (const float*)d_in[6];
  const float* k_norm = (const float*)d_in[7];
  const float* v_w = (const float*)d_in[8];
  const float* o_w = (const float*)d_in[9];
  const float* ln2 = (const float*)d_in[10];
  const float* gate_w = (const float*)d_in[11];
  const float* gate_s = (const float*)d_in[12];
  const float* up_w = (const float*)d_in[13];
  const float* up_s = (const float*)d_in[14];
  const float* down_w = (const float*)d_in[15];
  const float* down_s = (const float*)d_in[16];
  const float* fnorm = (const float*)d_in[17];
  const float* lm = (const float*)d_in[18];

  hipFuncSetAttribute((const void*)k_gemm256<0>,
                      hipFuncAttributeMaxDynamicSharedMemorySize, 131072);
  hipFuncSetAttribute((const void*)k_gemm256<1>,
                      hipFuncAttributeMaxDynamicSharedMemorySize, 131072);
  hipFuncSetAttribute((const void*)k_gemm256<2>,
                      hipFuncAttributeMaxDynamicSharedMemorySize, 131072);

  char* p = (char*)d_ws;
  auto alloc = [&](size_t n) { char* r = p; p += (n + 255) & ~(size_t)255; return r; };
  unsigned short* wbuf = (unsigned short*)alloc((size_t)VV * DD * 2);  // 131 MB
  float* h = (float*)alloc((size_t)TT * DD * 4);
  unsigned short* xb = (unsigned short*)alloc((size_t)TT * DD * 2);
  float* qkvf = (float*)alloc((size_t)2 * TT * 4096 * 4);              // 67 MB (2 partials)
  unsigned short* qb = (unsigned short*)alloc((size_t)NHEAD * TT * HDIM * 2);
  unsigned short* kb = (unsigned short*)alloc((size_t)KHEAD * TT * HDIM * 2);
  unsigned short* vT = (unsigned short*)alloc((size_t)KHEAD * HDIM * TT * 2);
  unsigned short* ob = (unsigned short*)alloc((size_t)TT * DD * 2);
  unsigned short* fuse = (unsigned short*)alloc((size_t)TT * FF * 2);
  // overlay inside wbuf (131.07 MB): dpart (split-K f32 partials, 67.1 MB)
  // at +56MiB: o-proj weight uses [0,8.4M), down weight [0,25.2M) -> ok
  float* dpart = (float*)((char*)wbuf + ((size_t)56 << 20));
  float* qpart1 = qkvf + (size_t)TT * 4096;
  const float sm = 0.08838834764831845f;  // 1/sqrt(128)

  k_embed_rms<<<TT, 256, 0, stream>>>(ids, embed, ln1, h, xb);
  for (int l = 0; l < LLAYERS; ++l) {
    // --- attention block: fused QKV GEMM (N=4096) split-K x2 on gemm256 ---
    k_wconv_qkv<<<2048, 256, 0, stream>>>(
        q_w + (size_t)l * DD * 2048, k_w + (size_t)l * DD * 1024,
        v_w + (size_t)l * DD * 1024, wbuf);
    k_gemm256<0><<<8 * (4096 / 256) * 2, 512, 131072, stream>>>(
        xb, wbuf, 4096, DD, 1024, 2, qkvf, nullptr, nullptr);
    k_qkv_post<<<14336, 256, 0, stream>>>(
        qkvf, qpart1, q_norm + (size_t)l * HDIM, k_norm + (size_t)l * HDIM, pos,
        qb, kb, vT, sm);
    k_attn<<<dim3(16, NHEAD), 256, 0, stream>>>(qb, kb, vT, ob);
    // --- o-proj on gemm256 split-K x4 + fused reduce/residual/ln2 ---
    k_wconv<false><<<dim3(DD / 64, 2048 / 64), 256, 0, stream>>>(
        o_w + (size_t)l * 2048 * DD, wbuf, 2048, DD);
    k_gemm256<0><<<8 * (DD / 256) * 4, 512, 131072, stream>>>(
        ob, wbuf, DD, 2048, 512, 4, dpart, nullptr, nullptr);
    k_sred_rms<<<TT, 256, 0, stream>>>(dpart, nullptr, h, ln2 + (size_t)l * DD, xb);
    // --- MLP block: interleaved gate|up GEMM with fused swiglu epilogue ---
    k_wconv_glu2<<<6144, 256, 0, stream>>>(
        gate_w + (size_t)l * DD * FF, up_w + (size_t)l * DD * FF, wbuf);
    k_gemm256<2><<<8 * (12288 / 256), 512, 131072, stream>>>(
        xb, wbuf, 12288, DD, DD, 1, fuse, gate_s + (size_t)l * FF,
        up_s + (size_t)l * FF);
    k_wconv<true><<<dim3(DD / 64, FF / 64), 256, 0, stream>>>(
        down_w + (size_t)l * FF * DD, wbuf, FF, DD);
    k_gemm256<0><<<8 * (DD / 256) * 4, 512, 131072, stream>>>(
        fuse, wbuf, DD, FF, 1536, 4, dpart, nullptr, nullptr);
    const float* gnext = (l + 1 < LLAYERS) ? (ln1 + (size_t)(l + 1) * DD) : fnorm;
    k_sred_rms<<<TT, 256, 0, stream>>>(dpart, down_s + (size_t)l * DD, h, gnext, xb);
  }
  // --- lm_head on the 8-phase kernel ---
  k_wconv<false><<<dim3(VV / 64, DD / 64), 256, 0, stream>>>(lm, wbuf, DD, VV);
  k_gemm256<0><<<8 * (VV / 256), 512, 131072, stream>>>(
      xb, wbuf, VV, DD, DD, 1, d_out, nullptr, nullptr);
}

// Round 13
// 1131.823 us; speedup vs baseline: 1.2906x; 1.0118x over previous
//
#include <hip/hip_runtime.h>

// Qwen3 forward: D=2048, N=16, K=8, H=128, F=6144, L=2, T=2048, V=32000
#define TT 2048
#define DD 2048
#define NHEAD 16
#define KHEAD 8
#define HDIM 128
#define FF 6144
#define LLAYERS 2
#define VV 32000

typedef __attribute__((ext_vector_type(8))) __bf16 bf16x8;
typedef __attribute__((ext_vector_type(4))) float f32x4;

__device__ __forceinline__ unsigned short f2bf(float x) {
  unsigned u = __float_as_uint(x);
  return (unsigned short)((u + 0x7FFFu + ((u >> 16) & 1u)) >> 16);
}

// f32 -> fp8 e4m3fn -> f32 round-trip (RNE), in-range weights only.
__device__ __forceinline__ float fp8_rt(float x) {
  float ax = fabsf(x);
  if (ax < 0.015625f) return rintf(x * 512.0f) * (1.0f / 512.0f);
  unsigned u = __float_as_uint(x);
  unsigned r = (u + 0x7FFFFu + ((u >> 20) & 1u)) & 0xFFF00000u;
  float y = __uint_as_float(r);
  if (fabsf(y) > 448.0f) y = copysignf(448.0f, x);
  return y;
}

__device__ __forceinline__ void gload16(const void* g, void* l) {
  __builtin_amdgcn_global_load_lds((__attribute__((address_space(1))) void*)g,
                                   (__attribute__((address_space(3))) void*)l,
                                   16, 0, 0);
}

// -------- embedding + RMSNorm(ln1, layer 0): ids -> h (f32) + xb (bf16) --------
__global__ void k_embed_rms(const int* __restrict__ ids, const float* __restrict__ embed,
                            const float* __restrict__ g, float* __restrict__ h,
                            unsigned short* __restrict__ out) {
  int t = blockIdx.x;
  const float4* src = (const float4*)(embed + (size_t)ids[t] * DD);
  float4 a = src[threadIdx.x], b = src[threadIdx.x + 256];
  float4* hrow = (float4*)(h + (size_t)t * DD);
  hrow[threadIdx.x] = a;
  hrow[threadIdx.x + 256] = b;
  float ss = a.x * a.x + a.y * a.y + a.z * a.z + a.w * a.w +
             b.x * b.x + b.y * b.y + b.z * b.z + b.w * b.w;
#pragma unroll
  for (int m = 32; m >= 1; m >>= 1) ss += __shfl_xor(ss, m);
  __shared__ float sred[4];
  int wid = threadIdx.x >> 6;
  if ((threadIdx.x & 63) == 0) sred[wid] = ss;
  __syncthreads();
  float tot = sred[0] + sred[1] + sred[2] + sred[3];
  float rn = 1.0f / sqrtf(tot * (1.0f / 2048.0f) + 1e-6f);
  const float4* gg = (const float4*)g;
  float4 g0 = gg[threadIdx.x], g1 = gg[threadIdx.x + 256];
  unsigned short* o0 = out + (size_t)t * DD + threadIdx.x * 4;
  unsigned short* o1 = o0 + 1024;
  *(ushort4*)o0 = make_ushort4(f2bf(a.x * rn * g0.x), f2bf(a.y * rn * g0.y),
                               f2bf(a.z * rn * g0.z), f2bf(a.w * rn * g0.w));
  *(ushort4*)o1 = make_ushort4(f2bf(b.x * rn * g1.x), f2bf(b.y * rn * g1.y),
                               f2bf(b.z * rn * g1.z), f2bf(b.w * rn * g1.w));
}

// -------- split-K(4) reduce [+opt col scale] + residual + RMSNorm(next g) --------
__global__ void k_sred_rms(const float* __restrict__ dp, const float* __restrict__ ds,
                           float* __restrict__ h, const float* __restrict__ g,
                           unsigned short* __restrict__ out) {
  int t = blockIdx.x;
  float4* hrow = (float4*)(h + (size_t)t * DD);
  float4 a = hrow[threadIdx.x], b = hrow[threadIdx.x + 256];
  float4 pa = {0.f, 0.f, 0.f, 0.f}, pb = {0.f, 0.f, 0.f, 0.f};
#pragma unroll
  for (int s = 0; s < 4; ++s) {
    const float4* pr = (const float4*)(dp + ((size_t)s * TT + t) * DD);
    float4 va = pr[threadIdx.x], vb = pr[threadIdx.x + 256];
    pa.x += va.x; pa.y += va.y; pa.z += va.z; pa.w += va.w;
    pb.x += vb.x; pb.y += vb.y; pb.z += vb.z; pb.w += vb.w;
  }
  if (ds) {
    const float4* dsc = (const float4*)ds;
    float4 s0 = dsc[threadIdx.x], s1 = dsc[threadIdx.x + 256];
    pa.x *= s0.x; pa.y *= s0.y; pa.z *= s0.z; pa.w *= s0.w;
    pb.x *= s1.x; pb.y *= s1.y; pb.z *= s1.z; pb.w *= s1.w;
  }
  a.x += pa.x; a.y += pa.y; a.z += pa.z; a.w += pa.w;
  b.x += pb.x; b.y += pb.y; b.z += pb.z; b.w += pb.w;
  hrow[threadIdx.x] = a;
  hrow[threadIdx.x + 256] = b;
  float ss = a.x * a.x + a.y * a.y + a.z * a.z + a.w * a.w +
             b.x * b.x + b.y * b.y + b.z * b.z + b.w * b.w;
#pragma unroll
  for (int m = 32; m >= 1; m >>= 1) ss += __shfl_xor(ss, m);
  __shared__ float sred[4];
  int wid = threadIdx.x >> 6;
  if ((threadIdx.x & 63) == 0) sred[wid] = ss;
  __syncthreads();
  float tot = sred[0] + sred[1] + sred[2] + sred[3];
  float rn = 1.0f / sqrtf(tot * (1.0f / 2048.0f) + 1e-6f);
  const float4* gg = (const float4*)g;
  float4 g0 = gg[threadIdx.x], g1 = gg[threadIdx.x + 256];
  unsigned short* o0 = out + (size_t)t * DD + threadIdx.x * 4;
  unsigned short* o1 = o0 + 1024;
  *(ushort4*)o0 = make_ushort4(f2bf(a.x * rn * g0.x), f2bf(a.y * rn * g0.y),
                               f2bf(a.z * rn * g0.z), f2bf(a.w * rn * g0.w));
  *(ushort4*)o1 = make_ushort4(f2bf(b.x * rn * g1.x), f2bf(b.y * rn * g1.y),
                               f2bf(b.z * rn * g1.z), f2bf(b.w * rn * g1.w));
}

// -------- weight convert body: W[Kd][Nd] f32 -> Wt[Nd][Kd] bf16 --------
template <bool QUANT>
__device__ __forceinline__ void wconv_body(const float* W, unsigned short* Wt,
                                           int Kd, int Nd, int bx, int by) {
  __shared__ float tile[64][65];
  int k0 = by * 64, n0 = bx * 64;
  int t = threadIdx.x;  // 256
#pragma unroll
  for (int i = 0; i < 4; ++i) {
    int row = (t >> 4) + i * 16, c4 = (t & 15) * 4;
    float4 v = *(const float4*)&W[(size_t)(k0 + row) * Nd + n0 + c4];
    tile[row][c4] = v.x; tile[row][c4 + 1] = v.y;
    tile[row][c4 + 2] = v.z; tile[row][c4 + 3] = v.w;
  }
  __syncthreads();
#pragma unroll
  for (int i = 0; i < 2; ++i) {
    int n = (t >> 3) + i * 32, kc = (t & 7) * 8;
    unsigned short r[8];
#pragma unroll
    for (int j = 0; j < 8; ++j) {
      float x = tile[kc + j][n];
      if (QUANT) x = fp8_rt(x);
      r[j] = f2bf(x);
    }
    unsigned short* o = &Wt[(size_t)(n0 + n) * Kd + k0 + kc];
    *(ushort4*)o = make_ushort4(r[0], r[1], r[2], r[3]);
    *(ushort4*)(o + 4) = make_ushort4(r[4], r[5], r[6], r[7]);
  }
}

template <bool QUANT>
__global__ void k_wconv(const float* __restrict__ W, unsigned short* __restrict__ Wt,
                        int Kd, int Nd) {
  wconv_body<QUANT>(W, Wt, Kd, Nd, blockIdx.x, blockIdx.y);
}

// -------- merged q|k|v weight convert (1 launch, 2048 blocks) --------
__global__ void k_wconv_qkv(const float* __restrict__ qw, const float* __restrict__ kw,
                            const float* __restrict__ vw, unsigned short* __restrict__ Wt) {
  int b = blockIdx.x;
  if (b < 1024) {
    wconv_body<false>(qw, Wt, DD, 2048, b & 31, b >> 5);
  } else if (b < 1536) {
    int lb = b - 1024;
    wconv_body<false>(kw, Wt + (size_t)2048 * DD, DD, 1024, lb & 15, lb >> 4);
  } else {
    int lb = b - 1536;
    wconv_body<false>(vw, Wt + (size_t)3072 * DD, DD, 1024, lb & 15, lb >> 4);
  }
}

// -------- merged gate|up convert with 16-col interleave (1 launch, 6144 blocks) --------
__device__ __forceinline__ void wconv_glu_body(const float* W, unsigned short* Wt,
                                               int bx, int by, int off) {
  __shared__ float tile[64][65];
  int k0 = by * 64, n0 = bx * 64;
  int t = threadIdx.x;
#pragma unroll
  for (int i = 0; i < 4; ++i) {
    int row = (t >> 4) + i * 16, c4 = (t & 15) * 4;
    float4 v = *(const float4*)&W[(size_t)(k0 + row) * FF + n0 + c4];
    tile[row][c4] = v.x; tile[row][c4 + 1] = v.y;
    tile[row][c4 + 2] = v.z; tile[row][c4 + 3] = v.w;
  }
  __syncthreads();
#pragma unroll
  for (int i = 0; i < 2; ++i) {
    int n = (t >> 3) + i * 32, kc = (t & 7) * 8;
    unsigned short r[8];
#pragma unroll
    for (int j = 0; j < 8; ++j) r[j] = f2bf(fp8_rt(tile[kc + j][n]));
    int lj = n0 + n;
    int phys = ((lj >> 4) << 5) + (lj & 15) + off;
    unsigned short* o = &Wt[(size_t)phys * DD + k0 + kc];
    *(ushort4*)o = make_ushort4(r[0], r[1], r[2], r[3]);
    *(ushort4*)(o + 4) = make_ushort4(r[4], r[5], r[6], r[7]);
  }
}

__global__ void k_wconv_glu2(const float* __restrict__ gw, const float* __restrict__ uw,
                             unsigned short* __restrict__ Wt) {
  int b = blockIdx.x;
  if (b < 3072) wconv_glu_body(gw, Wt, b % 96, b / 96, 0);
  else { int lb = b - 3072; wconv_glu_body(uw, Wt, lb % 96, lb / 96, 16); }
}

// ================= 256x256 8-phase GEMM, 1 barrier/phase, split-K =================
// (FROZEN verified R4/R10 structure: MfmaUtil ~47, 0 spills, 0 conflicts)
template <int PT, bool VM, class STG>
__device__ __forceinline__ void gphase(const char* smem, int BUF, int aRd, int bRd,
                                       bf16x8 (&af)[4][2], bf16x8 (&bfr)[2][2][2],
                                       f32x4 (&acc)[8][4], STG&& stage, bool vmzero) {
  constexpr int MH = (PT >= 2) ? 1 : 0;
  constexpr int NH = (PT == 1 || PT == 2) ? 1 : 0;
  if constexpr (PT == 0 || PT == 2) {
#pragma unroll
    for (int m = 0; m < 4; ++m) {
      int abase = BUF + aRd + MH * 8192 + m * 2048;
      af[m][0] = *(const bf16x8*)(smem + abase);
      af[m][1] = *(const bf16x8*)(smem + (abase ^ 64));
    }
  }
  if constexpr (PT <= 1) {
#pragma unroll
    for (int n = 0; n < 2; ++n) {
      int bbase = BUF + bRd + NH * 4096 + n * 2048;
      bfr[NH][n][0] = *(const bf16x8*)(smem + bbase);
      bfr[NH][n][1] = *(const bf16x8*)(smem + (bbase ^ 64));
    }
  }
  stage();
  if (VM) {
    if (vmzero) asm volatile("s_waitcnt vmcnt(0)" ::: "memory");
    else        asm volatile("s_waitcnt vmcnt(4)" ::: "memory");
  }
  __builtin_amdgcn_sched_barrier(0);
  __builtin_amdgcn_s_barrier();
  if constexpr (PT != 3) {
    asm volatile("s_waitcnt lgkmcnt(0)" ::: "memory");
    __builtin_amdgcn_sched_barrier(0);
  }
  __builtin_amdgcn_s_setprio(1);
#pragma unroll
  for (int kk = 0; kk < 2; ++kk)
#pragma unroll
    for (int m = 0; m < 4; ++m)
#pragma unroll
      for (int n = 0; n < 2; ++n)
        acc[MH * 4 + m][NH * 2 + n] = __builtin_amdgcn_mfma_f32_16x16x32_bf16(
            af[m][kk], bfr[NH][n][kk], acc[MH * 4 + m][NH * 2 + n], 0, 0, 0);
  __builtin_amdgcn_s_setprio(0);
  __builtin_amdgcn_sched_barrier(0);
}

// EPI: 0 = f32 store (to Cv + split*TT*N), 1 = bf16 store, 2 = swiglu-fused bf16
template <int EPI>
__global__ __launch_bounds__(512, 2) void k_gemm256(
    const unsigned short* __restrict__ A, const unsigned short* __restrict__ Bt,
    int N, int Kstride, int Kloop, int S, void* __restrict__ Cv,
    const float* __restrict__ gs, const float* __restrict__ us) {
  extern __shared__ __align__(16) char smem[];
  const int tid = threadIdx.x;
  const int lane = tid & 63, wid = tid >> 6;
  const int wm = wid >> 2, wn = wid & 3;
  const int l16 = lane & 15, lg = lane >> 4;
  const int l8 = lane >> 3, s8 = lane & 7;

  // XCD-aware bijective block swizzle (m204)
  const int nwg = gridDim.x;
  const int q = nwg >> 3, r = nwg & 7;
  const int xcd = blockIdx.x & 7, loc = blockIdx.x >> 3;
  const int wg = (xcd < r ? xcd * (q + 1) : r * (q + 1) + (xcd - r) * q) + loc;
  const int bm = wg & 7;
  const int t_ = wg >> 3;
  const int split = t_ % S, bn = t_ / S;
  const size_t m0 = (size_t)bm * 256, n0 = (size_t)bn * 256;
  const size_t kofs = (size_t)split * Kloop;

  const char* Ag = (const char*)(A + m0 * (size_t)Kstride + kofs);
  const char* Bg = (const char*)(Bt + n0 * (size_t)Kstride + kofs);
  const size_t sKA = (size_t)Kstride * 128;  // 64 rows * Kstride * 2B
  const size_t sKB = (size_t)Kstride * 64;   // 32 rows * Kstride * 2B
  const size_t aA = (size_t)(wid * 8 + l8) * Kstride * 2 + (size_t)((s8 ^ l8) << 4);
  const size_t aB = (size_t)((wid & 3) * 8 + l8) * Kstride * 2 + (size_t)((s8 ^ l8) << 4);

  auto stgA = [&](int BUF, int p, int kt) {
    gload16(Ag + aA + (size_t)p * sKA + (size_t)kt * 128,
            smem + BUF + p * 8192 + wid * 1024);
  };
  auto stgB = [&](int BUF, int qa, int qb, int kt) {
    int qq = (wid < 4) ? qa : qb;
    gload16(Bg + aB + (size_t)qq * sKB + (size_t)kt * 128,
            smem + BUF + 32768 + qq * 4096 + (wid & 3) * 1024);
  };
  auto stAev = [&](int BUF, int kt) { stgA(BUF, 0, kt); stgA(BUF, 2, kt); };
  auto stAod = [&](int BUF, int kt) { stgA(BUF, 1, kt); stgA(BUF, 3, kt); };
  auto stBev = [&](int BUF, int kt) { stgB(BUF, 0, 2, kt); stgB(BUF, 4, 6, kt); };
  auto stBod = [&](int BUF, int kt) { stgB(BUF, 1, 3, kt); stgB(BUF, 5, 7, kt); };

  const int colx = (lg << 4) ^ ((l16 & 7) << 4);
  const int aRd = (wm * 128 + l16) * 128 + colx;
  const int bRd = 32768 + (wn * 64 + l16) * 128 + colx;

  f32x4 acc[8][4] = {};
  bf16x8 af[4][2];
  bf16x8 bfr[2][2][2];

  // prologue: buf0 fully (t0), buf1 B-halves (t1); A(t1) staged at ph1/ph2.
  stAev(0, 0); stAod(0, 0); stBev(0, 0); stBod(0, 0);
  stBev(65536, 1); stBod(65536, 1);
  asm volatile("s_waitcnt vmcnt(4)" ::: "memory");
  __builtin_amdgcn_s_barrier();

  const int NIT = Kloop >> 7;  // pairs of K-tiles
#pragma unroll 1
  for (int i = 0; i < NIT; ++i) {
    const int t1 = 2 * i + 1, t2 = 2 * i + 2, t3 = 2 * i + 3;
    const bool more = (i + 1 < NIT);
    gphase<0, false>(smem, 0, aRd, bRd, af, bfr, acc, [&] { stAev(65536, t1); }, false);
    gphase<1, false>(smem, 0, aRd, bRd, af, bfr, acc, [&] { stAod(65536, t1); }, false);
    gphase<2, false>(smem, 0, aRd, bRd, af, bfr, acc, [&] { if (more) stBev(0, t2); }, false);
    gphase<3, true >(smem, 0, aRd, bRd, af, bfr, acc, [&] { if (more) stBod(0, t2); }, !more);
    gphase<0, false>(smem, 65536, aRd, bRd, af, bfr, acc, [&] { if (more) stAev(0, t2); }, false);
    gphase<1, false>(smem, 65536, aRd, bRd, af, bfr, acc, [&] { if (more) stAod(0, t2); }, false);
    gphase<2, false>(smem, 65536, aRd, bRd, af, bfr, acc, [&] { if (more) stBev(65536, t3); }, false);
    gphase<3, true >(smem, 65536, aRd, bRd, af, bfr, acc, [&] { if (more) stBod(65536, t3); }, false);
  }

  if constexpr (EPI == 2) {
    const int q0 = (int)((n0 + (size_t)wn * 64) >> 5);
    const float gsc0 = gs[q0 * 16 + l16], usc0 = us[q0 * 16 + l16];
    const float gsc1 = gs[(q0 + 1) * 16 + l16], usc1 = us[(q0 + 1) * 16 + l16];
    unsigned short* F = (unsigned short*)Cv;
#pragma unroll
    for (int m = 0; m < 8; ++m)
#pragma unroll
      for (int rr = 0; rr < 4; ++rr) {
        size_t row = m0 + wm * 128 + m * 16 + lg * 4 + rr;
        float g0 = acc[m][0][rr] * gsc0, u0 = acc[m][1][rr] * usc0;
        float g1 = acc[m][2][rr] * gsc1, u1 = acc[m][3][rr] * usc1;
        F[row * FF + q0 * 16 + l16] = f2bf((g0 / (1.0f + __expf(-g0))) * u0);
        F[row * FF + (q0 + 1) * 16 + l16] = f2bf((g1 / (1.0f + __expf(-g1))) * u1);
      }
  } else {
    char* Cb = (char*)Cv + (EPI == 0 ? (size_t)split * TT * N * 4 : 0);
#pragma unroll
    for (int m = 0; m < 8; ++m)
#pragma unroll
      for (int rr = 0; rr < 4; ++rr) {
        size_t row = m0 + wm * 128 + m * 16 + lg * 4 + rr;
#pragma unroll
        for (int n = 0; n < 4; ++n) {
          size_t col = n0 + wn * 64 + n * 16 + l16;
          float v = acc[m][n][rr];
          size_t idx = row * (size_t)N + col;
          if constexpr (EPI == 0) ((float*)Cb)[idx] = v;
          else ((unsigned short*)Cb)[idx] = f2bf(v);
        }
      }
  }
}

// ====== merged q-post | k-post | V-transpose (1 launch, 14336 blocks) ======
__device__ __forceinline__ void qk_post_body(const float* p0, const float* p1,
                                             const float* nscale, const int* pos,
                                             unsigned short* out, int nheads,
                                             int coloff, float qscale, int bx) {
  int gw = bx * 4 + (threadIdx.x >> 6);
  int t = gw / nheads, n = gw % nheads;
  int lane = threadIdx.x & 63;
  size_t base = (size_t)t * 4096 + coloff + n * HDIM;
  float x1 = p0[base + lane] + p1[base + lane];
  float x2 = p0[base + lane + 64] + p1[base + lane + 64];
  float ss = x1 * x1 + x2 * x2;
#pragma unroll
  for (int m = 32; m >= 1; m >>= 1) ss += __shfl_xor(ss, m);
  float rn = qscale / sqrtf(ss * (1.0f / 128.0f) + 1e-6f);
  x1 *= rn * nscale[lane];
  x2 *= rn * nscale[lane + 64];
  float p = (float)pos[t];
  float inv = powf(1.0e6f, -(float)lane / 64.0f);
  float fr = p * inv;
  float c = cosf(fr), s = sinf(fr);
  unsigned short* o = out + ((size_t)n * TT + t) * HDIM;
  o[lane] = f2bf(x1 * c - x2 * s);
  o[lane + 64] = f2bf(x2 * c + x1 * s);
}

__global__ void k_qkv_post(const float* __restrict__ p0, const float* __restrict__ p1,
                           const float* __restrict__ qn, const float* __restrict__ kn,
                           const int* __restrict__ pos, unsigned short* __restrict__ qb,
                           unsigned short* __restrict__ kb, unsigned short* __restrict__ vT,
                           float qscale) {
  int b = blockIdx.x;
  if (b < 8192) {
    qk_post_body(p0, p1, qn, pos, qb, NHEAD, 0, qscale, b);
  } else if (b < 12288) {
    qk_post_body(p0, p1, kn, pos, kb, KHEAD, 2048, 1.0f, b - 8192);
  } else {
    int lb = b - 12288;
    __shared__ float tile[32][33];
    int t0 = (lb & 63) * 32, h0 = (lb >> 6) * 32;
    int tx = threadIdx.x & 31, ty = threadIdx.x >> 5;
#pragma unroll
    for (int i = 0; i < 32; i += 8) {
      size_t idx = (size_t)(t0 + ty + i) * 4096 + 3072 + h0 + tx;
      tile[ty + i][tx] = p0[idx] + p1[idx];
    }
    __syncthreads();
    int kvh = h0 >> 7;
    int hh = h0 & 127;
#pragma unroll
    for (int i = 0; i < 32; i += 8) {
      float x = tile[tx][ty + i];
      vT[(size_t)kvh * HDIM * TT + (size_t)(hh + ty + i) * TT + t0 + tx] = f2bf(x);
    }
  }
}

// ====== flash attention, LDS-staged KV, pair-balanced + KV-parity split ======
// Block (j, head, half): q-blocks j and 31-j; processes KV-tiles t = half,
// half+2, ... < 32-j (group0 active while t <= j). Writes UNNORMALIZED partial
// (o, m, l) f32 to scratch; k_amerge combines the two halves exactly.
__global__ __launch_bounds__(256, 2) void k_attn(
    const unsigned short* __restrict__ Qb, const unsigned short* __restrict__ Kb,
    const unsigned short* __restrict__ Vt, float* __restrict__ po,
    float* __restrict__ ml) {
  __shared__ __align__(16) char kv[2][32768];           // [buf][ K 16KB | V 16KB ]
  __shared__ __align__(16) char Pl[4][2048];            // per-wave P [16][64] bf16
  const int tid = threadIdx.x;
  const int w = tid >> 6, lane = tid & 63;
  const int l16 = lane & 15, lg = lane >> 4;
  const int head = blockIdx.y, kvh = head >> 1;
  const int j = blockIdx.x;                             // 0..15
  const int half = blockIdx.z;                          // 0..1
  const int rbase[2] = {j * 64 + w * 16, (31 - j) * 64 + w * 16};

  bf16x8 qf[2][4];
#pragma unroll
  for (int qg = 0; qg < 2; ++qg) {
    const unsigned short* Qrow = Qb + ((size_t)head * TT + rbase[qg] + l16) * HDIM;
#pragma unroll
    for (int kc = 0; kc < 4; ++kc) qf[qg][kc] = *(const bf16x8*)&Qrow[kc * 32 + lg * 8];
  }

  const char* Kh = (const char*)(Kb + (size_t)kvh * TT * HDIM);
  const char* Vh = (const char*)(Vt + (size_t)kvh * HDIM * TT);

  auto stage = [&](int buf, int t) {
    const int kt0 = t * 64;
    char* bk = kv[buf];
    char* bv = kv[buf] + 16384;
#pragma unroll
    for (int it = 0; it < 4; ++it) {
      int rowK = it * 16 + w * 4 + (lane >> 4);
      gload16(Kh + (size_t)(kt0 + rowK) * 256 + (((lane & 15) ^ (rowK & 7)) << 4),
              bk + (it * 256 + w * 64) * 16);
      int rowV = it * 32 + w * 8 + (lane >> 3);
      gload16(Vh + (size_t)rowV * (TT * 2) + (size_t)kt0 * 2 +
                  (((lane & 7) ^ (rowV & 7)) << 4),
              bv + (it * 256 + w * 64) * 16);
    }
  };

  f32x4 o[2][8] = {};
  float m_[2][4], l_[2][4];
#pragma unroll
  for (int qg = 0; qg < 2; ++qg)
#pragma unroll
    for (int r = 0; r < 4; ++r) { m_[qg][r] = -1e30f; l_[qg][r] = 0.0f; }
  char* Pw = Pl[w];

  const int nt = 32 - j;  // exclusive upper bound on tile index
  stage(0, half);
  asm volatile("s_waitcnt vmcnt(0)" ::: "memory");
  __syncthreads();

  int itc = 0;
#pragma unroll 1
  for (int t = half; t < nt; t += 2, ++itc) {
    const int buf = itc & 1;
    const int kt0 = t * 64;
    if (t + 2 < nt) stage(buf ^ 1, t + 2);
    const char* bk = kv[buf];
    const char* bv = kv[buf] + 16384;

#pragma unroll
    for (int qg = 0; qg < 2; ++qg) {
      if (qg == 0 && t > j) continue;  // low q-block done (wave-uniform)
      f32x4 sg[4];
#pragma unroll
      for (int cg = 0; cg < 4; ++cg) {
        sg[cg] = f32x4{0.f, 0.f, 0.f, 0.f};
#pragma unroll
        for (int kc = 0; kc < 4; ++kc) {
          int row = cg * 16 + l16;
          int slot = kc * 4 + lg;
          bf16x8 kf = *(const bf16x8*)(bk + row * 256 + ((slot ^ (row & 7)) << 4));
          sg[cg] = __builtin_amdgcn_mfma_f32_16x16x32_bf16(qf[qg][kc], kf, sg[cg], 0, 0, 0);
        }
      }
      f32x4 mx;
#pragma unroll
      for (int r = 0; r < 4; ++r) {
        int row = rbase[qg] + 4 * lg + r;
        float a = sg[0][r]; if (kt0 + l16 > row) a = -1e30f; sg[0][r] = a;
        float b = sg[1][r]; if (kt0 + 16 + l16 > row) b = -1e30f; sg[1][r] = b;
        float c = sg[2][r]; if (kt0 + 32 + l16 > row) c = -1e30f; sg[2][r] = c;
        float d = sg[3][r]; if (kt0 + 48 + l16 > row) d = -1e30f; sg[3][r] = d;
        mx[r] = fmaxf(fmaxf(a, b), fmaxf(c, d));
      }
#pragma unroll
      for (int msk = 8; msk >= 1; msk >>= 1)
#pragma unroll
        for (int r = 0; r < 4; ++r) mx[r] = fmaxf(mx[r], __shfl_xor(mx[r], msk));
      float alpha[4];
#pragma unroll
      for (int r = 0; r < 4; ++r) {
        float mn = fmaxf(m_[qg][r], mx[r]);
        alpha[r] = __expf(m_[qg][r] - mn);
        m_[qg][r] = mn;
      }
      f32x4 rs;
#pragma unroll
      for (int r = 0; r < 4; ++r) {
        float s0 = __expf(sg[0][r] - m_[qg][r]);
        float s1 = __expf(sg[1][r] - m_[qg][r]);
        float s2 = __expf(sg[2][r] - m_[qg][r]);
        float s3 = __expf(sg[3][r] - m_[qg][r]);
        sg[0][r] = s0; sg[1][r] = s1; sg[2][r] = s2; sg[3][r] = s3;
        rs[r] = (s0 + s1) + (s2 + s3);
      }
#pragma unroll
      for (int msk = 8; msk >= 1; msk >>= 1)
#pragma unroll
        for (int r = 0; r < 4; ++r) rs[r] += __shfl_xor(rs[r], msk);
#pragma unroll
      for (int r = 0; r < 4; ++r) l_[qg][r] = l_[qg][r] * alpha[r] + rs[r];
#pragma unroll
      for (int hi = 0; hi < 8; ++hi)
#pragma unroll
        for (int r = 0; r < 4; ++r) o[qg][hi][r] *= alpha[r];

#pragma unroll
      for (int cg = 0; cg < 4; ++cg)
#pragma unroll
        for (int r = 0; r < 4; ++r) {
          int prow = 4 * lg + r;
          int slot = cg * 2 + (l16 >> 3);
          *(unsigned short*)(Pw + prow * 128 + ((slot ^ (prow & 7)) << 4) +
                             (l16 & 7) * 2) = f2bf(sg[cg][r]);
        }
      bf16x8 pf[2];
#pragma unroll
      for (int hf = 0; hf < 2; ++hf) {
        int slot = hf * 4 + lg;
        pf[hf] = *(const bf16x8*)(Pw + l16 * 128 + ((slot ^ (l16 & 7)) << 4));
      }
#pragma unroll
      for (int hi = 0; hi < 8; ++hi) {
        int row = hi * 16 + l16;
#pragma unroll
        for (int hf = 0; hf < 2; ++hf) {
          int slot = hf * 4 + lg;
          bf16x8 vf = *(const bf16x8*)(bv + row * 128 + ((slot ^ (row & 7)) << 4));
          o[qg][hi] = __builtin_amdgcn_mfma_f32_16x16x32_bf16(pf[hf], vf, o[qg][hi], 0, 0, 0);
        }
      }
    }
    asm volatile("s_waitcnt vmcnt(0)" ::: "memory");
    __syncthreads();
  }

  // write unnormalized partials: slot = ((j*16+head)*2 + half)*2 + qg
#pragma unroll
  for (int qg = 0; qg < 2; ++qg) {
    int sidx = (((j * 16 + head) * 2 + half) << 1) + qg;
    float* pob = po + (size_t)sidx * 8192;  // [64 rows][128]
    float* mlb = ml + (size_t)sidx * 128;   // [64 rows][m,l]
#pragma unroll
    for (int r = 0; r < 4; ++r) {
      int lrow = w * 16 + 4 * lg + r;
#pragma unroll
      for (int hi = 0; hi < 8; ++hi)
        pob[lrow * 128 + hi * 16 + l16] = o[qg][hi][r];
      if (l16 == 0) {
        mlb[lrow * 2] = m_[qg][r];
        mlb[lrow * 2 + 1] = l_[qg][r];
      }
    }
  }
}

// ====== merge the two KV-parity halves: exact flash combine -> bf16 ob ======
__global__ void k_amerge(const float* __restrict__ po, const float* __restrict__ ml,
                         unsigned short* __restrict__ Ob) {
  int b = blockIdx.x;  // j*32 + head*2 + grp
  int j = b >> 5, head = (b >> 1) & 15, grp = b & 1;
  int J = j * 16 + head;
  int s0 = (J << 2) + grp;       // half 0
  int s1 = (J << 2) + 2 + grp;   // half 1
  const float4* p04 = (const float4*)(po + (size_t)s0 * 8192);
  const float4* p14 = (const float4*)(po + (size_t)s1 * 8192);
  const float* ml0 = ml + (size_t)s0 * 128;
  const float* ml1 = ml + (size_t)s1 * 128;
  int trowbase = (grp ? (31 - j) : j) * 64;
  for (int i = threadIdx.x; i < 2048; i += 256) {
    int row = i >> 5, c4 = i & 31;
    float m0 = ml0[row * 2], l0 = ml0[row * 2 + 1];
    float m1 = ml1[row * 2], l1 = ml1[row * 2 + 1];
    float M = fmaxf(m0, m1);
    float w0 = __expf(m0 - M), w1 = __expf(m1 - M);
    float li = 1.0f / (l0 * w0 + l1 * w1);
    float4 a = p04[i], c = p14[i];
    unsigned short r0 = f2bf((a.x * w0 + c.x * w1) * li);
    unsigned short r1 = f2bf((a.y * w0 + c.y * w1) * li);
    unsigned short r2 = f2bf((a.z * w0 + c.z * w1) * li);
    unsigned short r3 = f2bf((a.w * w0 + c.w * w1) * li);
    *(ushort4*)&Ob[(size_t)(trowbase + row) * DD + head * HDIM + c4 * 4] =
        make_ushort4(r0, r1, r2, r3);
  }
}

extern "C" void kernel_launch(void* const* d_in, const int* in_sizes, int n_in,
                              void* d_out, int out_size, void* d_ws, size_t ws_size,
                              hipStream_t stream) {
  (void)in_sizes; (void)n_in; (void)out_size; (void)ws_size;
  const int* ids = (const int*)d_in[0];
  const int* pos = (const int*)d_in[1];
  const float* embed = (const float*)d_in[2];
  const float* ln1 = (const float*)d_in[3];
  const float* q_w = (const float*)d_in[4];
  const float* q_norm = (const float*)d_in[5];
  const float* k_w = (const float*)d_in[6];
  const float* k_norm = (const float*)d_in[7];
  const float* v_w = (const float*)d_in[8];
  const float* o_w = (const float*)d_in[9];
  const float* ln2 = (const float*)d_in[10];
  const float* gate_w = (const float*)d_in[11];
  const float* gate_s = (const float*)d_in[12];
  const float* up_w = (const float*)d_in[13];
  const float* up_s = (const float*)d_in[14];
  const float* down_w = (const float*)d_in[15];
  const float* down_s = (const float*)d_in[16];
  const float* fnorm = (const float*)d_in[17];
  const float* lm = (const float*)d_in[18];

  hipFuncSetAttribute((const void*)k_gemm256<0>,
                      hipFuncAttributeMaxDynamicSharedMemorySize, 131072);
  hipFuncSetAttribute((const void*)k_gemm256<1>,
                      hipFuncAttributeMaxDynamicSharedMemorySize, 131072);
  hipFuncSetAttribute((const void*)k_gemm256<2>,
                      hipFuncAttributeMaxDynamicSharedMemorySize, 131072);

  char* p = (char*)d_ws;
  auto alloc = [&](size_t n) { char* r = p; p += (n + 255) & ~(size_t)255; return r; };
  unsigned short* wbuf = (unsigned short*)alloc((size_t)VV * DD * 2);  // 131 MB
  float* h = (float*)alloc((size_t)TT * DD * 4);
  unsigned short* xb = (unsigned short*)alloc((size_t)TT * DD * 2);
  float* qkvf = (float*)alloc((size_t)2 * TT * 4096 * 4);              // 67 MB (2 partials)
  unsigned short* qb = (unsigned short*)alloc((size_t)NHEAD * TT * HDIM * 2);
  unsigned short* kb = (unsigned short*)alloc((size_t)KHEAD * TT * HDIM * 2);
  unsigned short* vT = (unsigned short*)alloc((size_t)KHEAD * HDIM * TT * 2);
  unsigned short* ob = (unsigned short*)alloc((size_t)TT * DD * 2);
  unsigned short* fuse = (unsigned short*)alloc((size_t)TT * FF * 2);
  // overlay inside wbuf (131.07 MB): dpart (split-K f32 partials, 67.1 MB)
  // at +56MiB: o-proj weight uses [0,8.4M), down weight [0,25.2M) -> ok
  float* dpart = (float*)((char*)wbuf + ((size_t)56 << 20));
  float* qpart1 = qkvf + (size_t)TT * 4096;
  // attention partial scratch overlaid on qkvf (free after k_qkv_post):
  float* apo = qkvf;                                   // 1024 x 64 x 128 f32 = 33.6 MB
  float* aml = qkvf + (size_t)1024 * 8192;             // 1024 x 64 x 2  f32 = 0.5 MB
  const float sm = 0.08838834764831845f;  // 1/sqrt(128)

  k_embed_rms<<<TT, 256, 0, stream>>>(ids, embed, ln1, h, xb);
  for (int l = 0; l < LLAYERS; ++l) {
    // --- attention block: fused QKV GEMM (N=4096) split-K x2 on gemm256 ---
    k_wconv_qkv<<<2048, 256, 0, stream>>>(
        q_w + (size_t)l * DD * 2048, k_w + (size_t)l * DD * 1024,
        v_w + (size_t)l * DD * 1024, wbuf);
    k_gemm256<0><<<8 * (4096 / 256) * 2, 512, 131072, stream>>>(
        xb, wbuf, 4096, DD, 1024, 2, qkvf, nullptr, nullptr);
    k_qkv_post<<<14336, 256, 0, stream>>>(
        qkvf, qpart1, q_norm + (size_t)l * HDIM, k_norm + (size_t)l * HDIM, pos,
        qb, kb, vT, sm);
    k_attn<<<dim3(16, NHEAD, 2), 256, 0, stream>>>(qb, kb, vT, apo, aml);
    k_amerge<<<512, 256, 0, stream>>>(apo, aml, ob);
    // --- o-proj on gemm256 split-K x4 + fused reduce/residual/ln2 ---
    k_wconv<false><<<dim3(DD / 64, 2048 / 64), 256, 0, stream>>>(
        o_w + (size_t)l * 2048 * DD, wbuf, 2048, DD);
    k_gemm256<0><<<8 * (DD / 256) * 4, 512, 131072, stream>>>(
        ob, wbuf, DD, 2048, 512, 4, dpart, nullptr, nullptr);
    k_sred_rms<<<TT, 256, 0, stream>>>(dpart, nullptr, h, ln2 + (size_t)l * DD, xb);
    // --- MLP block: interleaved gate|up GEMM with fused swiglu epilogue ---
    k_wconv_glu2<<<6144, 256, 0, stream>>>(
        gate_w + (size_t)l * DD * FF, up_w + (size_t)l * DD * FF, wbuf);
    k_gemm256<2><<<8 * (12288 / 256), 512, 131072, stream>>>(
        xb, wbuf, 12288, DD, DD, 1, fuse, gate_s + (size_t)l * FF,
        up_s + (size_t)l * FF);
    k_wconv<true><<<dim3(DD / 64, FF / 64), 256, 0, stream>>>(
        down_w + (size_t)l * FF * DD, wbuf, FF, DD);
    k_gemm256<0><<<8 * (DD / 256) * 4, 512, 131072, stream>>>(
        fuse, wbuf, DD, FF, 1536, 4, dpart, nullptr, nullptr);
    const float* gnext = (l + 1 < LLAYERS) ? (ln1 + (size_t)(l + 1) * DD) : fnorm;
    k_sred_rms<<<TT, 256, 0, stream>>>(dpart, down_s + (size_t)l * DD, h, gnext, xb);
  }
  // --- lm_head on the 8-phase kernel ---
  k_wconv<false><<<dim3(VV / 64, DD / 64), 256, 0, stream>>>(lm, wbuf, DD, VV);
  k_gemm256<0><<<8 * (VV / 256), 512, 131072, stream>>>(
      xb, wbuf, VV, DD, DD, 1, d_out, nullptr, nullptr);
}

// Round 14
// 1128.533 us; speedup vs baseline: 1.2944x; 1.0029x over previous
//
#include <hip/hip_runtime.h>

// Qwen3 forward: D=2048, N=16, K=8, H=128, F=6144, L=2, T=2048, V=32000
#define TT 2048
#define DD 2048
#define NHEAD 16
#define KHEAD 8
#define HDIM 128
#define FF 6144
#define LLAYERS 2
#define VV 32000

typedef __attribute__((ext_vector_type(8))) __bf16 bf16x8;
typedef __attribute__((ext_vector_type(4))) float f32x4;

__device__ __forceinline__ unsigned short f2bf(float x) {
  unsigned u = __float_as_uint(x);
  return (unsigned short)((u + 0x7FFFu + ((u >> 16) & 1u)) >> 16);
}

// f32 -> fp8 e4m3fn -> f32 round-trip (RNE), in-range weights only.
__device__ __forceinline__ float fp8_rt(float x) {
  float ax = fabsf(x);
  if (ax < 0.015625f) return rintf(x * 512.0f) * (1.0f / 512.0f);
  unsigned u = __float_as_uint(x);
  unsigned r = (u + 0x7FFFFu + ((u >> 20) & 1u)) & 0xFFF00000u;
  float y = __uint_as_float(r);
  if (fabsf(y) > 448.0f) y = copysignf(448.0f, x);
  return y;
}

__device__ __forceinline__ void gload16(const void* g, void* l) {
  __builtin_amdgcn_global_load_lds((__attribute__((address_space(1))) void*)g,
                                   (__attribute__((address_space(3))) void*)l,
                                   16, 0, 0);
}

// -------- embedding + RMSNorm(ln1, layer 0): ids -> h (f32) + xb (bf16) --------
__global__ void k_embed_rms(const int* __restrict__ ids, const float* __restrict__ embed,
                            const float* __restrict__ g, float* __restrict__ h,
                            unsigned short* __restrict__ out) {
  int t = blockIdx.x;
  const float4* src = (const float4*)(embed + (size_t)ids[t] * DD);
  float4 a = src[threadIdx.x], b = src[threadIdx.x + 256];
  float4* hrow = (float4*)(h + (size_t)t * DD);
  hrow[threadIdx.x] = a;
  hrow[threadIdx.x + 256] = b;
  float ss = a.x * a.x + a.y * a.y + a.z * a.z + a.w * a.w +
             b.x * b.x + b.y * b.y + b.z * b.z + b.w * b.w;
#pragma unroll
  for (int m = 32; m >= 1; m >>= 1) ss += __shfl_xor(ss, m);
  __shared__ float sred[4];
  int wid = threadIdx.x >> 6;
  if ((threadIdx.x & 63) == 0) sred[wid] = ss;
  __syncthreads();
  float tot = sred[0] + sred[1] + sred[2] + sred[3];
  float rn = 1.0f / sqrtf(tot * (1.0f / 2048.0f) + 1e-6f);
  const float4* gg = (const float4*)g;
  float4 g0 = gg[threadIdx.x], g1 = gg[threadIdx.x + 256];
  unsigned short* o0 = out + (size_t)t * DD + threadIdx.x * 4;
  unsigned short* o1 = o0 + 1024;
  *(ushort4*)o0 = make_ushort4(f2bf(a.x * rn * g0.x), f2bf(a.y * rn * g0.y),
                               f2bf(a.z * rn * g0.z), f2bf(a.w * rn * g0.w));
  *(ushort4*)o1 = make_ushort4(f2bf(b.x * rn * g1.x), f2bf(b.y * rn * g1.y),
                               f2bf(b.z * rn * g1.z), f2bf(b.w * rn * g1.w));
}

// -------- split-K(4) reduce [+opt col scale] + residual + RMSNorm(next g) --------
__global__ void k_sred_rms(const float* __restrict__ dp, const float* __restrict__ ds,
                           float* __restrict__ h, const float* __restrict__ g,
                           unsigned short* __restrict__ out) {
  int t = blockIdx.x;
  float4* hrow = (float4*)(h + (size_t)t * DD);
  float4 a = hrow[threadIdx.x], b = hrow[threadIdx.x + 256];
  float4 pa = {0.f, 0.f, 0.f, 0.f}, pb = {0.f, 0.f, 0.f, 0.f};
#pragma unroll
  for (int s = 0; s < 4; ++s) {
    const float4* pr = (const float4*)(dp + ((size_t)s * TT + t) * DD);
    float4 va = pr[threadIdx.x], vb = pr[threadIdx.x + 256];
    pa.x += va.x; pa.y += va.y; pa.z += va.z; pa.w += va.w;
    pb.x += vb.x; pb.y += vb.y; pb.z += vb.z; pb.w += vb.w;
  }
  if (ds) {
    const float4* dsc = (const float4*)ds;
    float4 s0 = dsc[threadIdx.x], s1 = dsc[threadIdx.x + 256];
    pa.x *= s0.x; pa.y *= s0.y; pa.z *= s0.z; pa.w *= s0.w;
    pb.x *= s1.x; pb.y *= s1.y; pb.z *= s1.z; pb.w *= s1.w;
  }
  a.x += pa.x; a.y += pa.y; a.z += pa.z; a.w += pa.w;
  b.x += pb.x; b.y += pb.y; b.z += pb.z; b.w += pb.w;
  hrow[threadIdx.x] = a;
  hrow[threadIdx.x + 256] = b;
  float ss = a.x * a.x + a.y * a.y + a.z * a.z + a.w * a.w +
             b.x * b.x + b.y * b.y + b.z * b.z + b.w * b.w;
#pragma unroll
  for (int m = 32; m >= 1; m >>= 1) ss += __shfl_xor(ss, m);
  __shared__ float sred[4];
  int wid = threadIdx.x >> 6;
  if ((threadIdx.x & 63) == 0) sred[wid] = ss;
  __syncthreads();
  float tot = sred[0] + sred[1] + sred[2] + sred[3];
  float rn = 1.0f / sqrtf(tot * (1.0f / 2048.0f) + 1e-6f);
  const float4* gg = (const float4*)g;
  float4 g0 = gg[threadIdx.x], g1 = gg[threadIdx.x + 256];
  unsigned short* o0 = out + (size_t)t * DD + threadIdx.x * 4;
  unsigned short* o1 = o0 + 1024;
  *(ushort4*)o0 = make_ushort4(f2bf(a.x * rn * g0.x), f2bf(a.y * rn * g0.y),
                               f2bf(a.z * rn * g0.z), f2bf(a.w * rn * g0.w));
  *(ushort4*)o1 = make_ushort4(f2bf(b.x * rn * g1.x), f2bf(b.y * rn * g1.y),
                               f2bf(b.z * rn * g1.z), f2bf(b.w * rn * g1.w));
}

// -------- weight convert body: W[Kd][Nd] f32 -> Wt[Nd][Kd] bf16 --------
template <bool QUANT>
__device__ __forceinline__ void wconv_body(const float* W, unsigned short* Wt,
                                           int Kd, int Nd, int bx, int by) {
  __shared__ float tile[64][65];
  int k0 = by * 64, n0 = bx * 64;
  int t = threadIdx.x;  // 256
#pragma unroll
  for (int i = 0; i < 4; ++i) {
    int row = (t >> 4) + i * 16, c4 = (t & 15) * 4;
    float4 v = *(const float4*)&W[(size_t)(k0 + row) * Nd + n0 + c4];
    tile[row][c4] = v.x; tile[row][c4 + 1] = v.y;
    tile[row][c4 + 2] = v.z; tile[row][c4 + 3] = v.w;
  }
  __syncthreads();
#pragma unroll
  for (int i = 0; i < 2; ++i) {
    int n = (t >> 3) + i * 32, kc = (t & 7) * 8;
    unsigned short r[8];
#pragma unroll
    for (int j = 0; j < 8; ++j) {
      float x = tile[kc + j][n];
      if (QUANT) x = fp8_rt(x);
      r[j] = f2bf(x);
    }
    unsigned short* o = &Wt[(size_t)(n0 + n) * Kd + k0 + kc];
    *(ushort4*)o = make_ushort4(r[0], r[1], r[2], r[3]);
    *(ushort4*)(o + 4) = make_ushort4(r[4], r[5], r[6], r[7]);
  }
}

template <bool QUANT>
__global__ void k_wconv(const float* __restrict__ W, unsigned short* __restrict__ Wt,
                        int Kd, int Nd) {
  wconv_body<QUANT>(W, Wt, Kd, Nd, blockIdx.x, blockIdx.y);
}

// -------- merged q|k|v|o weight convert (1 launch, 3072 blocks) --------
__global__ void k_wconv_qkvo(const float* __restrict__ qw, const float* __restrict__ kw,
                             const float* __restrict__ vw, const float* __restrict__ ow,
                             unsigned short* __restrict__ Wt) {
  int b = blockIdx.x;
  if (b < 1024) {
    wconv_body<false>(qw, Wt, DD, 2048, b & 31, b >> 5);
  } else if (b < 1536) {
    int lb = b - 1024;
    wconv_body<false>(kw, Wt + (size_t)2048 * DD, DD, 1024, lb & 15, lb >> 4);
  } else if (b < 2048) {
    int lb = b - 1536;
    wconv_body<false>(vw, Wt + (size_t)3072 * DD, DD, 1024, lb & 15, lb >> 4);
  } else {
    int lb = b - 2048;  // o-proj: W[2048][DD] -> Wt[DD][2048] at +4096*DD
    wconv_body<false>(ow, Wt + (size_t)4096 * DD, 2048, DD, lb & 31, lb >> 5);
  }
}

// -------- merged gate|up (16-col interleave) + down convert (1 launch, 9216 blocks) --------
__device__ __forceinline__ void wconv_glu_body(const float* W, unsigned short* Wt,
                                               int bx, int by, int off) {
  __shared__ float tile[64][65];
  int k0 = by * 64, n0 = bx * 64;
  int t = threadIdx.x;
#pragma unroll
  for (int i = 0; i < 4; ++i) {
    int row = (t >> 4) + i * 16, c4 = (t & 15) * 4;
    float4 v = *(const float4*)&W[(size_t)(k0 + row) * FF + n0 + c4];
    tile[row][c4] = v.x; tile[row][c4 + 1] = v.y;
    tile[row][c4 + 2] = v.z; tile[row][c4 + 3] = v.w;
  }
  __syncthreads();
#pragma unroll
  for (int i = 0; i < 2; ++i) {
    int n = (t >> 3) + i * 32, kc = (t & 7) * 8;
    unsigned short r[8];
#pragma unroll
    for (int j = 0; j < 8; ++j) r[j] = f2bf(fp8_rt(tile[kc + j][n]));
    int lj = n0 + n;
    int phys = ((lj >> 4) << 5) + (lj & 15) + off;
    unsigned short* o = &Wt[(size_t)phys * DD + k0 + kc];
    *(ushort4*)o = make_ushort4(r[0], r[1], r[2], r[3]);
    *(ushort4*)(o + 4) = make_ushort4(r[4], r[5], r[6], r[7]);
  }
}

__global__ void k_wconv_mlp(const float* __restrict__ gw, const float* __restrict__ uw,
                            const float* __restrict__ dw, unsigned short* __restrict__ Wt) {
  int b = blockIdx.x;
  if (b < 3072) {
    wconv_glu_body(gw, Wt, b % 96, b / 96, 0);
  } else if (b < 6144) {
    int lb = b - 3072;
    wconv_glu_body(uw, Wt, lb % 96, lb / 96, 16);
  } else {
    int lb = b - 6144;  // down: W[FF][DD] -> Wt[DD][FF] at +12288*DD (ushorts)
    wconv_body<true>(dw, Wt + (size_t)12288 * DD, FF, DD, lb & 31, lb >> 5);
  }
}

// ================= 256x256 8-phase GEMM, 1 barrier/phase, split-K =================
// (FROZEN verified R4/R10 structure: MfmaUtil ~47, 0 spills, 0 conflicts)
template <int PT, bool VM, class STG>
__device__ __forceinline__ void gphase(const char* smem, int BUF, int aRd, int bRd,
                                       bf16x8 (&af)[4][2], bf16x8 (&bfr)[2][2][2],
                                       f32x4 (&acc)[8][4], STG&& stage, bool vmzero) {
  constexpr int MH = (PT >= 2) ? 1 : 0;
  constexpr int NH = (PT == 1 || PT == 2) ? 1 : 0;
  if constexpr (PT == 0 || PT == 2) {
#pragma unroll
    for (int m = 0; m < 4; ++m) {
      int abase = BUF + aRd + MH * 8192 + m * 2048;
      af[m][0] = *(const bf16x8*)(smem + abase);
      af[m][1] = *(const bf16x8*)(smem + (abase ^ 64));
    }
  }
  if constexpr (PT <= 1) {
#pragma unroll
    for (int n = 0; n < 2; ++n) {
      int bbase = BUF + bRd + NH * 4096 + n * 2048;
      bfr[NH][n][0] = *(const bf16x8*)(smem + bbase);
      bfr[NH][n][1] = *(const bf16x8*)(smem + (bbase ^ 64));
    }
  }
  stage();
  if (VM) {
    if (vmzero) asm volatile("s_waitcnt vmcnt(0)" ::: "memory");
    else        asm volatile("s_waitcnt vmcnt(4)" ::: "memory");
  }
  __builtin_amdgcn_sched_barrier(0);
  __builtin_amdgcn_s_barrier();
  if constexpr (PT != 3) {
    asm volatile("s_waitcnt lgkmcnt(0)" ::: "memory");
    __builtin_amdgcn_sched_barrier(0);
  }
  __builtin_amdgcn_s_setprio(1);
#pragma unroll
  for (int kk = 0; kk < 2; ++kk)
#pragma unroll
    for (int m = 0; m < 4; ++m)
#pragma unroll
      for (int n = 0; n < 2; ++n)
        acc[MH * 4 + m][NH * 2 + n] = __builtin_amdgcn_mfma_f32_16x16x32_bf16(
            af[m][kk], bfr[NH][n][kk], acc[MH * 4 + m][NH * 2 + n], 0, 0, 0);
  __builtin_amdgcn_s_setprio(0);
  __builtin_amdgcn_sched_barrier(0);
}

// EPI: 0 = f32 store (to Cv + split*TT*N), 1 = bf16 store, 2 = swiglu-fused bf16
template <int EPI>
__global__ __launch_bounds__(512, 2) void k_gemm256(
    const unsigned short* __restrict__ A, const unsigned short* __restrict__ Bt,
    int N, int Kstride, int Kloop, int S, void* __restrict__ Cv,
    const float* __restrict__ gs, const float* __restrict__ us) {
  extern __shared__ __align__(16) char smem[];
  const int tid = threadIdx.x;
  const int lane = tid & 63, wid = tid >> 6;
  const int wm = wid >> 2, wn = wid & 3;
  const int l16 = lane & 15, lg = lane >> 4;
  const int l8 = lane >> 3, s8 = lane & 7;

  // XCD-aware bijective block swizzle (m204)
  const int nwg = gridDim.x;
  const int q = nwg >> 3, r = nwg & 7;
  const int xcd = blockIdx.x & 7, loc = blockIdx.x >> 3;
  const int wg = (xcd < r ? xcd * (q + 1) : r * (q + 1) + (xcd - r) * q) + loc;
  const int bm = wg & 7;
  const int t_ = wg >> 3;
  const int split = t_ % S, bn = t_ / S;
  const size_t m0 = (size_t)bm * 256, n0 = (size_t)bn * 256;
  const size_t kofs = (size_t)split * Kloop;

  const char* Ag = (const char*)(A + m0 * (size_t)Kstride + kofs);
  const char* Bg = (const char*)(Bt + n0 * (size_t)Kstride + kofs);
  const size_t sKA = (size_t)Kstride * 128;  // 64 rows * Kstride * 2B
  const size_t sKB = (size_t)Kstride * 64;   // 32 rows * Kstride * 2B
  const size_t aA = (size_t)(wid * 8 + l8) * Kstride * 2 + (size_t)((s8 ^ l8) << 4);
  const size_t aB = (size_t)((wid & 3) * 8 + l8) * Kstride * 2 + (size_t)((s8 ^ l8) << 4);

  auto stgA = [&](int BUF, int p, int kt) {
    gload16(Ag + aA + (size_t)p * sKA + (size_t)kt * 128,
            smem + BUF + p * 8192 + wid * 1024);
  };
  auto stgB = [&](int BUF, int qa, int qb, int kt) {
    int qq = (wid < 4) ? qa : qb;
    gload16(Bg + aB + (size_t)qq * sKB + (size_t)kt * 128,
            smem + BUF + 32768 + qq * 4096 + (wid & 3) * 1024);
  };
  auto stAev = [&](int BUF, int kt) { stgA(BUF, 0, kt); stgA(BUF, 2, kt); };
  auto stAod = [&](int BUF, int kt) { stgA(BUF, 1, kt); stgA(BUF, 3, kt); };
  auto stBev = [&](int BUF, int kt) { stgB(BUF, 0, 2, kt); stgB(BUF, 4, 6, kt); };
  auto stBod = [&](int BUF, int kt) { stgB(BUF, 1, 3, kt); stgB(BUF, 5, 7, kt); };

  const int colx = (lg << 4) ^ ((l16 & 7) << 4);
  const int aRd = (wm * 128 + l16) * 128 + colx;
  const int bRd = 32768 + (wn * 64 + l16) * 128 + colx;

  f32x4 acc[8][4] = {};
  bf16x8 af[4][2];
  bf16x8 bfr[2][2][2];

  // prologue: buf0 fully (t0), buf1 B-halves (t1); A(t1) staged at ph1/ph2.
  stAev(0, 0); stAod(0, 0); stBev(0, 0); stBod(0, 0);
  stBev(65536, 1); stBod(65536, 1);
  asm volatile("s_waitcnt vmcnt(4)" ::: "memory");
  __builtin_amdgcn_s_barrier();

  const int NIT = Kloop >> 7;  // pairs of K-tiles
#pragma unroll 1
  for (int i = 0; i < NIT; ++i) {
    const int t1 = 2 * i + 1, t2 = 2 * i + 2, t3 = 2 * i + 3;
    const bool more = (i + 1 < NIT);
    gphase<0, false>(smem, 0, aRd, bRd, af, bfr, acc, [&] { stAev(65536, t1); }, false);
    gphase<1, false>(smem, 0, aRd, bRd, af, bfr, acc, [&] { stAod(65536, t1); }, false);
    gphase<2, false>(smem, 0, aRd, bRd, af, bfr, acc, [&] { if (more) stBev(0, t2); }, false);
    gphase<3, true >(smem, 0, aRd, bRd, af, bfr, acc, [&] { if (more) stBod(0, t2); }, !more);
    gphase<0, false>(smem, 65536, aRd, bRd, af, bfr, acc, [&] { if (more) stAev(0, t2); }, false);
    gphase<1, false>(smem, 65536, aRd, bRd, af, bfr, acc, [&] { if (more) stAod(0, t2); }, false);
    gphase<2, false>(smem, 65536, aRd, bRd, af, bfr, acc, [&] { if (more) stBev(65536, t3); }, false);
    gphase<3, true >(smem, 65536, aRd, bRd, af, bfr, acc, [&] { if (more) stBod(65536, t3); }, false);
  }

  if constexpr (EPI == 2) {
    const int q0 = (int)((n0 + (size_t)wn * 64) >> 5);
    const float gsc0 = gs[q0 * 16 + l16], usc0 = us[q0 * 16 + l16];
    const float gsc1 = gs[(q0 + 1) * 16 + l16], usc1 = us[(q0 + 1) * 16 + l16];
    unsigned short* F = (unsigned short*)Cv;
#pragma unroll
    for (int m = 0; m < 8; ++m)
#pragma unroll
      for (int rr = 0; rr < 4; ++rr) {
        size_t row = m0 + wm * 128 + m * 16 + lg * 4 + rr;
        float g0 = acc[m][0][rr] * gsc0, u0 = acc[m][1][rr] * usc0;
        float g1 = acc[m][2][rr] * gsc1, u1 = acc[m][3][rr] * usc1;
        F[row * FF + q0 * 16 + l16] = f2bf((g0 / (1.0f + __expf(-g0))) * u0);
        F[row * FF + (q0 + 1) * 16 + l16] = f2bf((g1 / (1.0f + __expf(-g1))) * u1);
      }
  } else {
    char* Cb = (char*)Cv + (EPI == 0 ? (size_t)split * TT * N * 4 : 0);
#pragma unroll
    for (int m = 0; m < 8; ++m)
#pragma unroll
      for (int rr = 0; rr < 4; ++rr) {
        size_t row = m0 + wm * 128 + m * 16 + lg * 4 + rr;
#pragma unroll
        for (int n = 0; n < 4; ++n) {
          size_t col = n0 + wn * 64 + n * 16 + l16;
          float v = acc[m][n][rr];
          size_t idx = row * (size_t)N + col;
          if constexpr (EPI == 0) ((float*)Cb)[idx] = v;
          else ((unsigned short*)Cb)[idx] = f2bf(v);
        }
      }
  }
}

// ====== merged q-post | k-post | V-transpose (1 launch, 14336 blocks) ======
__device__ __forceinline__ void qk_post_body(const float* p0, const float* p1,
                                             const float* nscale, const int* pos,
                                             unsigned short* out, int nheads,
                                             int coloff, float qscale, int bx) {
  int gw = bx * 4 + (threadIdx.x >> 6);
  int t = gw / nheads, n = gw % nheads;
  int lane = threadIdx.x & 63;
  size_t base = (size_t)t * 4096 + coloff + n * HDIM;
  float x1 = p0[base + lane] + p1[base + lane];
  float x2 = p0[base + lane + 64] + p1[base + lane + 64];
  float ss = x1 * x1 + x2 * x2;
#pragma unroll
  for (int m = 32; m >= 1; m >>= 1) ss += __shfl_xor(ss, m);
  float rn = qscale / sqrtf(ss * (1.0f / 128.0f) + 1e-6f);
  x1 *= rn * nscale[lane];
  x2 *= rn * nscale[lane + 64];
  float p = (float)pos[t];
  float inv = powf(1.0e6f, -(float)lane / 64.0f);
  float fr = p * inv;
  float c = cosf(fr), s = sinf(fr);
  unsigned short* o = out + ((size_t)n * TT + t) * HDIM;
  o[lane] = f2bf(x1 * c - x2 * s);
  o[lane + 64] = f2bf(x2 * c + x1 * s);
}

__global__ void k_qkv_post(const float* __restrict__ p0, const float* __restrict__ p1,
                           const float* __restrict__ qn, const float* __restrict__ kn,
                           const int* __restrict__ pos, unsigned short* __restrict__ qb,
                           unsigned short* __restrict__ kb, unsigned short* __restrict__ vT,
                           float qscale) {
  int b = blockIdx.x;
  if (b < 8192) {
    qk_post_body(p0, p1, qn, pos, qb, NHEAD, 0, qscale, b);
  } else if (b < 12288) {
    qk_post_body(p0, p1, kn, pos, kb, KHEAD, 2048, 1.0f, b - 8192);
  } else {
    int lb = b - 12288;
    __shared__ float tile[32][33];
    int t0 = (lb & 63) * 32, h0 = (lb >> 6) * 32;
    int tx = threadIdx.x & 31, ty = threadIdx.x >> 5;
#pragma unroll
    for (int i = 0; i < 32; i += 8) {
      size_t idx = (size_t)(t0 + ty + i) * 4096 + 3072 + h0 + tx;
      tile[ty + i][tx] = p0[idx] + p1[idx];
    }
    __syncthreads();
    int kvh = h0 >> 7;
    int hh = h0 & 127;
#pragma unroll
    for (int i = 0; i < 32; i += 8) {
      float x = tile[tx][ty + i];
      vT[(size_t)kvh * HDIM * TT + (size_t)(hh + ty + i) * TT + t0 + tx] = f2bf(x);
    }
  }
}

// ====== flash attention, LDS-staged KV, pair-balanced + KV-parity split ======
__global__ __launch_bounds__(256, 2) void k_attn(
    const unsigned short* __restrict__ Qb, const unsigned short* __restrict__ Kb,
    const unsigned short* __restrict__ Vt, float* __restrict__ po,
    float* __restrict__ ml) {
  __shared__ __align__(16) char kv[2][32768];           // [buf][ K 16KB | V 16KB ]
  __shared__ __align__(16) char Pl[4][2048];            // per-wave P [16][64] bf16
  const int tid = threadIdx.x;
  const int w = tid >> 6, lane = tid & 63;
  const int l16 = lane & 15, lg = lane >> 4;
  const int head = blockIdx.y, kvh = head >> 1;
  const int j = blockIdx.x;                             // 0..15
  const int half = blockIdx.z;                          // 0..1
  const int rbase[2] = {j * 64 + w * 16, (31 - j) * 64 + w * 16};

  bf16x8 qf[2][4];
#pragma unroll
  for (int qg = 0; qg < 2; ++qg) {
    const unsigned short* Qrow = Qb + ((size_t)head * TT + rbase[qg] + l16) * HDIM;
#pragma unroll
    for (int kc = 0; kc < 4; ++kc) qf[qg][kc] = *(const bf16x8*)&Qrow[kc * 32 + lg * 8];
  }

  const char* Kh = (const char*)(Kb + (size_t)kvh * TT * HDIM);
  const char* Vh = (const char*)(Vt + (size_t)kvh * HDIM * TT);

  auto stage = [&](int buf, int t) {
    const int kt0 = t * 64;
    char* bk = kv[buf];
    char* bv = kv[buf] + 16384;
#pragma unroll
    for (int it = 0; it < 4; ++it) {
      int rowK = it * 16 + w * 4 + (lane >> 4);
      gload16(Kh + (size_t)(kt0 + rowK) * 256 + (((lane & 15) ^ (rowK & 7)) << 4),
              bk + (it * 256 + w * 64) * 16);
      int rowV = it * 32 + w * 8 + (lane >> 3);
      gload16(Vh + (size_t)rowV * (TT * 2) + (size_t)kt0 * 2 +
                  (((lane & 7) ^ (rowV & 7)) << 4),
              bv + (it * 256 + w * 64) * 16);
    }
  };

  f32x4 o[2][8] = {};
  float m_[2][4], l_[2][4];
#pragma unroll
  for (int qg = 0; qg < 2; ++qg)
#pragma unroll
    for (int r = 0; r < 4; ++r) { m_[qg][r] = -1e30f; l_[qg][r] = 0.0f; }
  char* Pw = Pl[w];

  const int nt = 32 - j;  // exclusive upper bound on tile index
  stage(0, half);
  asm volatile("s_waitcnt vmcnt(0)" ::: "memory");
  __syncthreads();

  int itc = 0;
#pragma unroll 1
  for (int t = half; t < nt; t += 2, ++itc) {
    const int buf = itc & 1;
    const int kt0 = t * 64;
    if (t + 2 < nt) stage(buf ^ 1, t + 2);
    const char* bk = kv[buf];
    const char* bv = kv[buf] + 16384;

#pragma unroll
    for (int qg = 0; qg < 2; ++qg) {
      if (qg == 0 && t > j) continue;  // low q-block done (wave-uniform)
      f32x4 sg[4];
#pragma unroll
      for (int cg = 0; cg < 4; ++cg) {
        sg[cg] = f32x4{0.f, 0.f, 0.f, 0.f};
#pragma unroll
        for (int kc = 0; kc < 4; ++kc) {
          int row = cg * 16 + l16;
          int slot = kc * 4 + lg;
          bf16x8 kf = *(const bf16x8*)(bk + row * 256 + ((slot ^ (row & 7)) << 4));
          sg[cg] = __builtin_amdgcn_mfma_f32_16x16x32_bf16(qf[qg][kc], kf, sg[cg], 0, 0, 0);
        }
      }
      f32x4 mx;
#pragma unroll
      for (int r = 0; r < 4; ++r) {
        int row = rbase[qg] + 4 * lg + r;
        float a = sg[0][r]; if (kt0 + l16 > row) a = -1e30f; sg[0][r] = a;
        float b = sg[1][r]; if (kt0 + 16 + l16 > row) b = -1e30f; sg[1][r] = b;
        float c = sg[2][r]; if (kt0 + 32 + l16 > row) c = -1e30f; sg[2][r] = c;
        float d = sg[3][r]; if (kt0 + 48 + l16 > row) d = -1e30f; sg[3][r] = d;
        mx[r] = fmaxf(fmaxf(a, b), fmaxf(c, d));
      }
#pragma unroll
      for (int msk = 8; msk >= 1; msk >>= 1)
#pragma unroll
        for (int r = 0; r < 4; ++r) mx[r] = fmaxf(mx[r], __shfl_xor(mx[r], msk));
      float alpha[4];
#pragma unroll
      for (int r = 0; r < 4; ++r) {
        float mn = fmaxf(m_[qg][r], mx[r]);
        alpha[r] = __expf(m_[qg][r] - mn);
        m_[qg][r] = mn;
      }
      f32x4 rs;
#pragma unroll
      for (int r = 0; r < 4; ++r) {
        float s0 = __expf(sg[0][r] - m_[qg][r]);
        float s1 = __expf(sg[1][r] - m_[qg][r]);
        float s2 = __expf(sg[2][r] - m_[qg][r]);
        float s3 = __expf(sg[3][r] - m_[qg][r]);
        sg[0][r] = s0; sg[1][r] = s1; sg[2][r] = s2; sg[3][r] = s3;
        rs[r] = (s0 + s1) + (s2 + s3);
      }
#pragma unroll
      for (int msk = 8; msk >= 1; msk >>= 1)
#pragma unroll
        for (int r = 0; r < 4; ++r) rs[r] += __shfl_xor(rs[r], msk);
#pragma unroll
      for (int r = 0; r < 4; ++r) l_[qg][r] = l_[qg][r] * alpha[r] + rs[r];
#pragma unroll
      for (int hi = 0; hi < 8; ++hi)
#pragma unroll
        for (int r = 0; r < 4; ++r) o[qg][hi][r] *= alpha[r];

#pragma unroll
      for (int cg = 0; cg < 4; ++cg)
#pragma unroll
        for (int r = 0; r < 4; ++r) {
          int prow = 4 * lg + r;
          int slot = cg * 2 + (l16 >> 3);
          *(unsigned short*)(Pw + prow * 128 + ((slot ^ (prow & 7)) << 4) +
                             (l16 & 7) * 2) = f2bf(sg[cg][r]);
        }
      bf16x8 pf[2];
#pragma unroll
      for (int hf = 0; hf < 2; ++hf) {
        int slot = hf * 4 + lg;
        pf[hf] = *(const bf16x8*)(Pw + l16 * 128 + ((slot ^ (l16 & 7)) << 4));
      }
#pragma unroll
      for (int hi = 0; hi < 8; ++hi) {
        int row = hi * 16 + l16;
#pragma unroll
        for (int hf = 0; hf < 2; ++hf) {
          int slot = hf * 4 + lg;
          bf16x8 vf = *(const bf16x8*)(bv + row * 128 + ((slot ^ (row & 7)) << 4));
          o[qg][hi] = __builtin_amdgcn_mfma_f32_16x16x32_bf16(pf[hf], vf, o[qg][hi], 0, 0, 0);
        }
      }
    }
    asm volatile("s_waitcnt vmcnt(0)" ::: "memory");
    __syncthreads();
  }

  // write unnormalized partials: slot = ((j*16+head)*2 + half)*2 + qg
#pragma unroll
  for (int qg = 0; qg < 2; ++qg) {
    int sidx = (((j * 16 + head) * 2 + half) << 1) + qg;
    float* pob = po + (size_t)sidx * 8192;  // [64 rows][128]
    float* mlb = ml + (size_t)sidx * 128;   // [64 rows][m,l]
#pragma unroll
    for (int r = 0; r < 4; ++r) {
      int lrow = w * 16 + 4 * lg + r;
#pragma unroll
      for (int hi = 0; hi < 8; ++hi)
        pob[lrow * 128 + hi * 16 + l16] = o[qg][hi][r];
      if (l16 == 0) {
        mlb[lrow * 2] = m_[qg][r];
        mlb[lrow * 2 + 1] = l_[qg][r];
      }
    }
  }
}

// ====== merge the two KV-parity halves: exact flash combine -> bf16 ob ======
__global__ void k_amerge(const float* __restrict__ po, const float* __restrict__ ml,
                         unsigned short* __restrict__ Ob) {
  int b = blockIdx.x;  // j*32 + head*2 + grp
  int j = b >> 5, head = (b >> 1) & 15, grp = b & 1;
  int J = j * 16 + head;
  int s0 = (J << 2) + grp;       // half 0
  int s1 = (J << 2) + 2 + grp;   // half 1
  const float4* p04 = (const float4*)(po + (size_t)s0 * 8192);
  const float4* p14 = (const float4*)(po + (size_t)s1 * 8192);
  const float* ml0 = ml + (size_t)s0 * 128;
  const float* ml1 = ml + (size_t)s1 * 128;
  int trowbase = (grp ? (31 - j) : j) * 64;
  for (int i = threadIdx.x; i < 2048; i += 256) {
    int row = i >> 5, c4 = i & 31;
    float m0 = ml0[row * 2], l0 = ml0[row * 2 + 1];
    float m1 = ml1[row * 2], l1 = ml1[row * 2 + 1];
    float M = fmaxf(m0, m1);
    float w0 = __expf(m0 - M), w1 = __expf(m1 - M);
    float li = 1.0f / (l0 * w0 + l1 * w1);
    float4 a = p04[i], c = p14[i];
    unsigned short r0 = f2bf((a.x * w0 + c.x * w1) * li);
    unsigned short r1 = f2bf((a.y * w0 + c.y * w1) * li);
    unsigned short r2 = f2bf((a.z * w0 + c.z * w1) * li);
    unsigned short r3 = f2bf((a.w * w0 + c.w * w1) * li);
    *(ushort4*)&Ob[(size_t)(trowbase + row) * DD + head * HDIM + c4 * 4] =
        make_ushort4(r0, r1, r2, r3);
  }
}

extern "C" void kernel_launch(void* const* d_in, const int* in_sizes, int n_in,
                              void* d_out, int out_size, void* d_ws, size_t ws_size,
                              hipStream_t stream) {
  (void)in_sizes; (void)n_in; (void)out_size; (void)ws_size;
  const int* ids = (const int*)d_in[0];
  const int* pos = (const int*)d_in[1];
  const float* embed = (const float*)d_in[2];
  const float* ln1 = (const float*)d_in[3];
  const float* q_w = (const float*)d_in[4];
  const float* q_norm = (const float*)d_in[5];
  const float* k_w = (const float*)d_in[6];
  const float* k_norm = (const float*)d_in[7];
  const float* v_w = (const float*)d_in[8];
  const float* o_w = (const float*)d_in[9];
  const float* ln2 = (const float*)d_in[10];
  const float* gate_w = (const float*)d_in[11];
  const float* gate_s = (const float*)d_in[12];
  const float* up_w = (const float*)d_in[13];
  const float* up_s = (const float*)d_in[14];
  const float* down_w = (const float*)d_in[15];
  const float* down_s = (const float*)d_in[16];
  const float* fnorm = (const float*)d_in[17];
  const float* lm = (const float*)d_in[18];

  hipFuncSetAttribute((const void*)k_gemm256<0>,
                      hipFuncAttributeMaxDynamicSharedMemorySize, 131072);
  hipFuncSetAttribute((const void*)k_gemm256<1>,
                      hipFuncAttributeMaxDynamicSharedMemorySize, 131072);
  hipFuncSetAttribute((const void*)k_gemm256<2>,
                      hipFuncAttributeMaxDynamicSharedMemorySize, 131072);

  char* p = (char*)d_ws;
  auto alloc = [&](size_t n) { char* r = p; p += (n + 255) & ~(size_t)255; return r; };
  unsigned short* wbuf = (unsigned short*)alloc((size_t)VV * DD * 2);  // 131 MB
  float* h = (float*)alloc((size_t)TT * DD * 4);
  unsigned short* xb = (unsigned short*)alloc((size_t)TT * DD * 2);
  float* qkvf = (float*)alloc((size_t)2 * TT * 4096 * 4);              // 67 MB scratch
  unsigned short* qb = (unsigned short*)alloc((size_t)NHEAD * TT * HDIM * 2);
  unsigned short* kb = (unsigned short*)alloc((size_t)KHEAD * TT * HDIM * 2);
  unsigned short* vT = (unsigned short*)alloc((size_t)KHEAD * HDIM * TT * 2);
  unsigned short* ob = (unsigned short*)alloc((size_t)TT * DD * 2);
  unsigned short* fuse = (unsigned short*)alloc((size_t)TT * FF * 2);
  // qkvf scratch lifetimes (all in-stream sequential, verified disjoint):
  //  - qkv split-K f32 partials (2x33.5MB) : gemm_qkv -> qkv_post
  //  - attn partials apo/aml (34.1MB)      : k_attn -> k_amerge
  //  - dpart split-K f32 partials (67.1MB) : gemm_o/gemm_down -> k_sred_rms
  float* qpart1 = qkvf + (size_t)TT * 4096;
  float* apo = qkvf;
  float* aml = qkvf + (size_t)1024 * 8192;
  float* dpart = qkvf;
  const float sm = 0.08838834764831845f;  // 1/sqrt(128)

  k_embed_rms<<<TT, 256, 0, stream>>>(ids, embed, ln1, h, xb);
  for (int l = 0; l < LLAYERS; ++l) {
    // --- attention block ---
    k_wconv_qkvo<<<3072, 256, 0, stream>>>(
        q_w + (size_t)l * DD * 2048, k_w + (size_t)l * DD * 1024,
        v_w + (size_t)l * DD * 1024, o_w + (size_t)l * 2048 * DD, wbuf);
    k_gemm256<0><<<8 * (4096 / 256) * 2, 512, 131072, stream>>>(
        xb, wbuf, 4096, DD, 1024, 2, qkvf, nullptr, nullptr);
    k_qkv_post<<<14336, 256, 0, stream>>>(
        qkvf, qpart1, q_norm + (size_t)l * HDIM, k_norm + (size_t)l * HDIM, pos,
        qb, kb, vT, sm);
    k_attn<<<dim3(16, NHEAD, 2), 256, 0, stream>>>(qb, kb, vT, apo, aml);
    k_amerge<<<512, 256, 0, stream>>>(apo, aml, ob);
    // o-proj on gemm256 split-K x4 + fused reduce/residual/ln2
    k_gemm256<0><<<8 * (DD / 256) * 4, 512, 131072, stream>>>(
        ob, wbuf + (size_t)4096 * DD, DD, 2048, 512, 4, dpart, nullptr, nullptr);
    k_sred_rms<<<TT, 256, 0, stream>>>(dpart, nullptr, h, ln2 + (size_t)l * DD, xb);
    // --- MLP block ---
    k_wconv_mlp<<<9216, 256, 0, stream>>>(
        gate_w + (size_t)l * DD * FF, up_w + (size_t)l * DD * FF,
        down_w + (size_t)l * FF * DD, wbuf);
    k_gemm256<2><<<8 * (12288 / 256), 512, 131072, stream>>>(
        xb, wbuf, 12288, DD, DD, 1, fuse, gate_s + (size_t)l * FF,
        up_s + (size_t)l * FF);
    k_gemm256<0><<<8 * (DD / 256) * 4, 512, 131072, stream>>>(
        fuse, wbuf + (size_t)12288 * DD, DD, FF, 1536, 4, dpart, nullptr, nullptr);
    const float* gnext = (l + 1 < LLAYERS) ? (ln1 + (size_t)(l + 1) * DD) : fnorm;
    k_sred_rms<<<TT, 256, 0, stream>>>(dpart, down_s + (size_t)l * DD, h, gnext, xb);
  }
  // --- lm_head on the 8-phase kernel ---
  k_wconv<false><<<dim3(VV / 64, DD / 64), 256, 0, stream>>>(lm, wbuf, DD, VV);
  k_gemm256<0><<<8 * (VV / 256), 512, 131072, stream>>>(
      xb, wbuf, VV, DD, DD, 1, d_out, nullptr, nullptr);
}